// Round 1
// baseline (296.953 us; speedup 1.0000x reference)
//
#include <hip/hip_runtime.h>
#include <hip/hip_bf16.h>

typedef __bf16 bf16_t;
typedef __attribute__((ext_vector_type(8))) __bf16 bf16x8;
typedef __attribute__((ext_vector_type(4))) float f32x4;

#define B_   8
#define C_   512
#define S_   1024
#define NH   8
#define HD   64
#define C3_  1536

// ---------------------------------------------------------------------------
// GroupNorm (32 groups of 16 ch) fused with bf16 cast + transpose:
// x[b][c][s] (f32) -> h_t[b][s][c] (bf16)
// ---------------------------------------------------------------------------
__global__ __launch_bounds__(256) void gn_transpose_kernel(
    const float* __restrict__ x, const float* __restrict__ scale,
    const float* __restrict__ bias, bf16_t* __restrict__ h_t) {
  int b = blockIdx.x >> 5, g = blockIdx.x & 31;
  int tid = threadIdx.x;
  const float* xb = x + ((size_t)b * C_ + g * 16) * S_;

  float s = 0.f, s2 = 0.f;
  for (int i = tid; i < 16 * S_; i += 256) {
    float v = xb[i];
    s += v; s2 += v * v;
  }
  for (int off = 32; off > 0; off >>= 1) {
    s  += __shfl_down(s, off);
    s2 += __shfl_down(s2, off);
  }
  __shared__ float red[8];
  int wave = tid >> 6, lane = tid & 63;
  if (lane == 0) { red[wave] = s; red[4 + wave] = s2; }
  __syncthreads();
  float ts = red[0] + red[1] + red[2] + red[3];
  float t2 = red[4] + red[5] + red[6] + red[7];
  const float inv_n = 1.f / (16.f * S_);
  float mean = ts * inv_n;
  float var  = t2 * inv_n - mean * mean;
  float rstd = rsqrtf(var + 1e-6f);

  __shared__ bf16_t T[256 * 17];
  for (int chunk = 0; chunk < 4; ++chunk) {
    int s0 = chunk * 256;
    __syncthreads();
    for (int cl = 0; cl < 16; ++cl) {
      float v = xb[cl * S_ + s0 + tid];
      float y = (v - mean) * rstd * scale[g * 16 + cl] + bias[g * 16 + cl];
      T[tid * 17 + cl] = (bf16_t)y;
    }
    __syncthreads();
    int c = tid & 15, sb = tid >> 4;
    for (int j = 0; j < 16; ++j) {
      int sl = sb + j * 16;
      h_t[((size_t)b * S_ + s0 + sl) * C_ + g * 16 + c] = T[sl * 17 + c];
    }
  }
}

// ---------------------------------------------------------------------------
// Transpose f32 weight W[R][Ccols] -> bf16 Wt[Ccols][R]
// ---------------------------------------------------------------------------
__global__ __launch_bounds__(256) void transpose_w_kernel(
    const float* __restrict__ W, bf16_t* __restrict__ Wt, int R, int Ccols) {
  __shared__ float T[32 * 33];
  int c0 = blockIdx.x * 32, r0 = blockIdx.y * 32;
  int tid = threadIdx.x;
  int lc = tid & 31, lr = tid >> 5;
  for (int i = 0; i < 4; ++i) {
    int r = lr + i * 8;
    T[r * 33 + lc] = W[(size_t)(r0 + r) * Ccols + c0 + lc];
  }
  __syncthreads();
  for (int i = 0; i < 4; ++i) {
    int cc = lr + i * 8;
    Wt[(size_t)(c0 + cc) * R + r0 + lc] = (bf16_t)T[lc * 33 + cc];
  }
}

// ---------------------------------------------------------------------------
// QKV GEMM: out[b][s][d] = sum_c h_t[b][s][c] * Wt[d][c] + bias[d]  (bf16 out)
// M=s (1024), N=d (1536), K=c (512).  Tile 64x64, 4 waves (16 rows each).
// ---------------------------------------------------------------------------
__global__ __launch_bounds__(256) void gemm_qkv_kernel(
    const bf16_t* __restrict__ A, const bf16_t* __restrict__ Bw,
    const float* __restrict__ bias, bf16_t* __restrict__ out) {
  int bz = blockIdx.z;
  int row0 = blockIdx.y * 64 + (threadIdx.x >> 6) * 16;
  int col0 = blockIdx.x * 64;
  int lane = threadIdx.x & 63;
  int lr = lane & 15, lq = lane >> 4;
  const bf16_t* Ap = A + ((size_t)bz * S_ + row0 + lr) * C_ + lq * 8;
  f32x4 acc[4] = {};
  for (int k0 = 0; k0 < C_; k0 += 32) {
    bf16x8 a = *(const bf16x8*)(Ap + k0);
#pragma unroll
    for (int nf = 0; nf < 4; ++nf) {
      bf16x8 bb = *(const bf16x8*)(Bw + (size_t)(col0 + nf * 16 + lr) * C_ + k0 + lq * 8);
      acc[nf] = __builtin_amdgcn_mfma_f32_16x16x32_bf16(a, bb, acc[nf], 0, 0, 0);
    }
  }
#pragma unroll
  for (int nf = 0; nf < 4; ++nf) {
    int col = col0 + nf * 16 + lr;
    float bv = bias[col];
#pragma unroll
    for (int r = 0; r < 4; ++r) {
      int row = row0 + lq * 4 + r;
      out[((size_t)bz * S_ + row) * C3_ + col] = (bf16_t)(acc[nf][r] + bv);
    }
  }
}

// ---------------------------------------------------------------------------
// Flash attention: qkv_t[b][s][3C] -> ao[b][s][C]  (bf16)
// Per (b, head, 64-row q tile). 4 waves x 16 q rows. KBLK=64, online softmax.
// q ch = h*192+d, k ch = h*192+64+d, v ch = h*192+128+d; out ch = h*64+d.
// ---------------------------------------------------------------------------
__global__ __launch_bounds__(256) void attn_kernel(
    const bf16_t* __restrict__ qkv, bf16_t* __restrict__ ao) {
  int qt = blockIdx.x, head = blockIdx.y, b = blockIdx.z;
  int tid = threadIdx.x, wave = tid >> 6, lane = tid & 63;
  int lr = lane & 15, lq = lane >> 4;
  const bf16_t* base = qkv + (size_t)b * S_ * C3_;
  int s0 = qt * 64;

  bf16x8 aq[2];
  {
    int qrow = s0 + wave * 16 + lr;
    aq[0] = *(const bf16x8*)(base + (size_t)qrow * C3_ + head * 192 + 0  + lq * 8);
    aq[1] = *(const bf16x8*)(base + (size_t)qrow * C3_ + head * 192 + 32 + lq * 8);
  }

  __shared__ bf16_t Vt[64 * 80];       // V^T tile: [d][t], row stride 80
  __shared__ bf16_t Pl[4 * 16 * 80];   // per-wave P tile: [qrow][t]
  bf16_t* Plw = Pl + wave * 16 * 80;

  f32x4 oacc[4] = {};
  float m_run[4], l_run[4];
#pragma unroll
  for (int r = 0; r < 4; ++r) { m_run[r] = -1e30f; l_run[r] = 0.f; }
  const float sc = 0.125f;  // 1/sqrt(64)

  for (int kt = 0; kt < 16; ++kt) {
    int t0 = kt * 64;
    __syncthreads();  // previous PV done before overwriting Vt
    // stage V^T into LDS (reads coalesced over d)
    for (int i = 0; i < 8; ++i) {
      int idx = i * 256 + tid;
      int tr = idx >> 5, d2 = (idx & 31) * 2;
      const bf16_t* vp = base + (size_t)(t0 + tr) * C3_ + head * 192 + 128 + d2;
      Vt[(d2    ) * 80 + tr] = vp[0];
      Vt[(d2 + 1) * 80 + tr] = vp[1];
    }
    __syncthreads();

    // S = Q K^T (16x64 per wave), K read direct from global
    f32x4 sacc[4] = {};
#pragma unroll
    for (int kk = 0; kk < 2; ++kk) {
#pragma unroll
      for (int nf = 0; nf < 4; ++nf) {
        bf16x8 bk = *(const bf16x8*)(base + (size_t)(t0 + nf * 16 + lr) * C3_ +
                                     head * 192 + 64 + kk * 32 + lq * 8);
        sacc[nf] = __builtin_amdgcn_mfma_f32_16x16x32_bf16(aq[kk], bk, sacc[nf], 0, 0, 0);
      }
    }

    // online softmax over t (row spread across 16-lane group, 4 cols/lane)
    float p[4][4], alpha[4];
#pragma unroll
    for (int r = 0; r < 4; ++r) {
      float mx = -1e30f;
#pragma unroll
      for (int nf = 0; nf < 4; ++nf) mx = fmaxf(mx, sacc[nf][r] * sc);
      for (int off = 1; off < 16; off <<= 1) mx = fmaxf(mx, __shfl_xor(mx, off));
      float mn = fmaxf(m_run[r], mx);
      alpha[r] = __expf(m_run[r] - mn);
      m_run[r] = mn;
      float rs = 0.f;
#pragma unroll
      for (int nf = 0; nf < 4; ++nf) {
        float v = __expf(sacc[nf][r] * sc - mn);
        p[nf][r] = v; rs += v;
      }
      for (int off = 1; off < 16; off <<= 1) rs += __shfl_xor(rs, off);
      l_run[r] = l_run[r] * alpha[r] + rs;
    }
#pragma unroll
    for (int df = 0; df < 4; ++df)
#pragma unroll
      for (int r = 0; r < 4; ++r) oacc[df][r] *= alpha[r];

    // P -> bf16 -> LDS (A-operand layout for PV)
#pragma unroll
    for (int nf = 0; nf < 4; ++nf)
#pragma unroll
      for (int r = 0; r < 4; ++r)
        Plw[(lq * 4 + r) * 80 + nf * 16 + lr] = (bf16_t)p[nf][r];
    __syncthreads();

    // O += P V
#pragma unroll
    for (int kk = 0; kk < 2; ++kk) {
      bf16x8 ap = *(const bf16x8*)(Plw + (size_t)lr * 80 + kk * 32 + lq * 8);
#pragma unroll
      for (int df = 0; df < 4; ++df) {
        bf16x8 bv = *(const bf16x8*)(Vt + (size_t)(df * 16 + lr) * 80 + kk * 32 + lq * 8);
        oacc[df] = __builtin_amdgcn_mfma_f32_16x16x32_bf16(ap, bv, oacc[df], 0, 0, 0);
      }
    }
  }

  // epilogue: O / l, write ao[b][s][head*64 + d]
#pragma unroll
  for (int r = 0; r < 4; ++r) {
    float inv = 1.f / l_run[r];
    int srow = s0 + wave * 16 + lq * 4 + r;
#pragma unroll
    for (int df = 0; df < 4; ++df)
      ao[((size_t)b * S_ + srow) * C_ + head * HD + df * 16 + lr] =
          (bf16_t)(oacc[df][r] * inv);
  }
}

// ---------------------------------------------------------------------------
// Out projection + bias + residual:
// out[b][d][s] = x[b][d][s] + bias[d] + sum_c ao[b][s][c] * WoT[d][c]
// M=d (512), N=s (1024), K=c (512). f32 output.
// ---------------------------------------------------------------------------
__global__ __launch_bounds__(256) void gemm_out_kernel(
    const bf16_t* __restrict__ A, const bf16_t* __restrict__ Bm,
    const float* __restrict__ bias, const float* __restrict__ xres,
    float* __restrict__ out) {
  int bz = blockIdx.z;
  int row0 = blockIdx.y * 64 + (threadIdx.x >> 6) * 16;  // d
  int col0 = blockIdx.x * 64;                            // s
  int lane = threadIdx.x & 63;
  int lr = lane & 15, lq = lane >> 4;
  const bf16_t* Ap = A + (size_t)(row0 + lr) * C_ + lq * 8;
  const bf16_t* Bp = Bm + ((size_t)bz * S_ + col0 + lr) * C_ + lq * 8;
  f32x4 acc[4] = {};
  for (int k0 = 0; k0 < C_; k0 += 32) {
    bf16x8 a = *(const bf16x8*)(Ap + k0);
#pragma unroll
    for (int nf = 0; nf < 4; ++nf) {
      bf16x8 bb = *(const bf16x8*)(Bp + (size_t)nf * 16 * C_ + k0);
      acc[nf] = __builtin_amdgcn_mfma_f32_16x16x32_bf16(a, bb, acc[nf], 0, 0, 0);
    }
  }
#pragma unroll
  for (int r = 0; r < 4; ++r) {
    int row = row0 + lq * 4 + r;
    float bv = bias[row];
#pragma unroll
    for (int nf = 0; nf < 4; ++nf) {
      int col = col0 + nf * 16 + lr;
      size_t o = ((size_t)bz * C_ + row) * S_ + col;
      out[o] = xres[o] + bv + acc[nf][r];
    }
  }
}

// ---------------------------------------------------------------------------
extern "C" void kernel_launch(void* const* d_in, const int* in_sizes, int n_in,
                              void* d_out, int out_size, void* d_ws, size_t ws_size,
                              hipStream_t stream) {
  const float* x        = (const float*)d_in[0];
  const float* gn_scale = (const float*)d_in[1];
  const float* gn_bias  = (const float*)d_in[2];
  const float* W_qkv    = (const float*)d_in[3];
  const float* b_qkv    = (const float*)d_in[4];
  const float* W_out    = (const float*)d_in[5];
  const float* b_out    = (const float*)d_in[6];
  float* out = (float*)d_out;

  char* ws = (char*)d_ws;
  bf16_t* h_t   = (bf16_t*)(ws);                       // 8*1024*512  bf16 = 8 MiB
  bf16_t* qkv_t = (bf16_t*)(ws + 8388608);             // 8*1024*1536 bf16 = 24 MiB
  bf16_t* ao_t  = (bf16_t*)(ws + 33554432);            // 8*1024*512  bf16 = 8 MiB
  bf16_t* wqkvt = (bf16_t*)(ws + 41943040);            // 1536*512 bf16
  bf16_t* woutt = (bf16_t*)(ws + 43515904);            // 512*512 bf16

  transpose_w_kernel<<<dim3(48, 16), 256, 0, stream>>>(W_qkv, wqkvt, C_, C3_);
  transpose_w_kernel<<<dim3(16, 16), 256, 0, stream>>>(W_out, woutt, C_, C_);
  gn_transpose_kernel<<<256, 256, 0, stream>>>(x, gn_scale, gn_bias, h_t);
  gemm_qkv_kernel<<<dim3(24, 16, 8), 256, 0, stream>>>(h_t, wqkvt, b_qkv, qkv_t);
  attn_kernel<<<dim3(16, 8, 8), 256, 0, stream>>>(qkv_t, ao_t);
  gemm_out_kernel<<<dim3(16, 8, 8), 256, 0, stream>>>(woutt, ao_t, b_out, x, out);
}

// Round 2
// 226.725 us; speedup vs baseline: 1.3098x; 1.3098x over previous
//
#include <hip/hip_runtime.h>
#include <hip/hip_bf16.h>

typedef __bf16 bf16_t;
typedef __attribute__((ext_vector_type(8))) __bf16 bf16x8;
typedef __attribute__((ext_vector_type(4))) float f32x4;
typedef __attribute__((ext_vector_type(4))) unsigned int u32x4;

#define B_   8
#define C_   512
#define S_   1024
#define NH   8
#define HD   64
#define C3_  1536
#define C2_  1024

static __device__ __forceinline__ unsigned pack2(float a, float b) {
  unsigned short lo = __builtin_bit_cast(unsigned short, (__bf16)a);
  unsigned short hi = __builtin_bit_cast(unsigned short, (__bf16)b);
  return (unsigned)lo | ((unsigned)hi << 16);
}

// ---------------------------------------------------------------------------
// GroupNorm (32 groups of 16 ch) fused with bf16 cast + transpose:
// x[b][c][s] (f32) -> h_t[b][s][c] (bf16)
// ---------------------------------------------------------------------------
__global__ __launch_bounds__(256) void gn_transpose_kernel(
    const float* __restrict__ x, const float* __restrict__ scale,
    const float* __restrict__ bias, bf16_t* __restrict__ h_t) {
  int b = blockIdx.x >> 5, g = blockIdx.x & 31;
  int tid = threadIdx.x;
  const float* xb = x + ((size_t)b * C_ + g * 16) * S_;

  float s = 0.f, s2 = 0.f;
  for (int i = tid; i < 16 * S_; i += 256) {
    float v = xb[i];
    s += v; s2 += v * v;
  }
  for (int off = 32; off > 0; off >>= 1) {
    s  += __shfl_down(s, off);
    s2 += __shfl_down(s2, off);
  }
  __shared__ float red[8];
  int wave = tid >> 6, lane = tid & 63;
  if (lane == 0) { red[wave] = s; red[4 + wave] = s2; }
  __syncthreads();
  float ts = red[0] + red[1] + red[2] + red[3];
  float t2 = red[4] + red[5] + red[6] + red[7];
  const float inv_n = 1.f / (16.f * S_);
  float mean = ts * inv_n;
  float var  = t2 * inv_n - mean * mean;
  float rstd = rsqrtf(var + 1e-6f);

  __shared__ bf16_t T[256 * 17];
  for (int chunk = 0; chunk < 4; ++chunk) {
    int s0 = chunk * 256;
    __syncthreads();
    for (int cl = 0; cl < 16; ++cl) {
      float v = xb[cl * S_ + s0 + tid];
      float y = (v - mean) * rstd * scale[g * 16 + cl] + bias[g * 16 + cl];
      T[tid * 17 + cl] = (bf16_t)y;
    }
    __syncthreads();
    int c = tid & 15, sb = tid >> 4;
    for (int j = 0; j < 16; ++j) {
      int sl = sb + j * 16;
      h_t[((size_t)b * S_ + s0 + sl) * C_ + g * 16 + c] = T[sl * 17 + c];
    }
  }
}

// ---------------------------------------------------------------------------
// Transpose f32 weight W[R][Ccols] -> bf16 Wt[Ccols][R]
// ---------------------------------------------------------------------------
__global__ __launch_bounds__(256) void transpose_w_kernel(
    const float* __restrict__ W, bf16_t* __restrict__ Wt, int R, int Ccols) {
  __shared__ float T[32 * 33];
  int c0 = blockIdx.x * 32, r0 = blockIdx.y * 32;
  int tid = threadIdx.x;
  int lc = tid & 31, lr = tid >> 5;
  for (int i = 0; i < 4; ++i) {
    int r = lr + i * 8;
    T[r * 33 + lc] = W[(size_t)(r0 + r) * Ccols + c0 + lc];
  }
  __syncthreads();
  for (int i = 0; i < 4; ++i) {
    int cc = lr + i * 8;
    Wt[(size_t)(c0 + cc) * R + r0 + lc] = (bf16_t)T[lc * 33 + cc];
  }
}

// ---------------------------------------------------------------------------
// QKV GEMM: val[row=(b,s)][d] = sum_c h_t[row][c] * Wt[d][c] + bias[d]
// 128x128 tile, 4 waves as 2x2, 4x4 frags/wave.
// Epilogue splits: Q (scaled 0.125) and K -> qk[b][s][h*128 + det],
//                  V -> vt[b][h][dv][s]  (transposed for the PV MFMA).
// ---------------------------------------------------------------------------
__global__ __launch_bounds__(256) void gemm_qkv_kernel(
    const bf16_t* __restrict__ A, const bf16_t* __restrict__ Bw,
    const float* __restrict__ bias, bf16_t* __restrict__ qk,
    bf16_t* __restrict__ vt) {
  int n0 = blockIdx.x * 128;  // d in [0,1536)
  int m0 = blockIdx.y * 128;  // (b,s) row in [0,8192)
  int wave = threadIdx.x >> 6, lane = threadIdx.x & 63;
  int wr = wave >> 1, wc = wave & 1;
  int lr = lane & 15, lq = lane >> 4;
  const bf16_t* Ap = A + (size_t)(m0 + wr * 64 + lr) * C_ + lq * 8;
  const bf16_t* Bp = Bw + (size_t)(n0 + wc * 64 + lr) * C_ + lq * 8;
  f32x4 acc[4][4] = {};
#pragma unroll 2
  for (int k0 = 0; k0 < C_; k0 += 32) {
    bf16x8 a[4], bb[4];
#pragma unroll
    for (int i = 0; i < 4; ++i) {
      a[i]  = *(const bf16x8*)(Ap + (size_t)i * 16 * C_ + k0);
      bb[i] = *(const bf16x8*)(Bp + (size_t)i * 16 * C_ + k0);
    }
#pragma unroll
    for (int i = 0; i < 4; ++i)
#pragma unroll
      for (int j = 0; j < 4; ++j)
        acc[i][j] = __builtin_amdgcn_mfma_f32_16x16x32_bf16(a[i], bb[j], acc[i][j], 0, 0, 0);
  }
#pragma unroll
  for (int j = 0; j < 4; ++j) {
    int d = n0 + wc * 64 + j * 16 + lr;
    int h = d / 192, det = d - h * 192;
    float bv = bias[d];
    bool isv = det >= 128;
    float scl = det < 64 ? 0.125f : 1.f;
#pragma unroll
    for (int i = 0; i < 4; ++i) {
#pragma unroll
      for (int r = 0; r < 4; ++r) {
        int row = m0 + wr * 64 + i * 16 + lq * 4 + r;
        int b_ = row >> 10, s = row & 1023;
        float val = acc[i][j][r] + bv;
        if (!isv)
          qk[((size_t)b_ * S_ + s) * C2_ + h * 128 + det] = (bf16_t)(val * scl);
        else
          vt[((size_t)(b_ * NH + h) * HD + (det - 128)) * S_ + s] = (bf16_t)val;
      }
    }
  }
}

// ---------------------------------------------------------------------------
// Flash attention, barrier-free, LDS-free.
// Per block: (qt, head, b); 4 waves x 16 q rows. KBLK=64.
// Swapped QK^T: sacc = mfma(K, Q) -> S^T; each lane owns one q row.
// P redistributed to PV B-frags via in-register shuffles.
// ---------------------------------------------------------------------------
__global__ __launch_bounds__(256) void attn_kernel(
    const bf16_t* __restrict__ qk, const bf16_t* __restrict__ vt,
    bf16_t* __restrict__ ao) {
  int qt = blockIdx.x, head = blockIdx.y, b = blockIdx.z;
  int tid = threadIdx.x, wave = tid >> 6, lane = tid & 63;
  int lr = lane & 15, lq = lane >> 4;
  int qb = qt * 64 + wave * 16;
  const bf16_t* qkb = qk + (size_t)b * S_ * C2_ + head * 128;
  const bf16_t* vtb = vt + (size_t)(b * NH + head) * HD * S_;

  bf16x8 qf0 = *(const bf16x8*)(qkb + (size_t)(qb + lr) * C2_ + lq * 8);
  bf16x8 qf1 = *(const bf16x8*)(qkb + (size_t)(qb + lr) * C2_ + 32 + lq * 8);

  f32x4 oacc[4] = {};
  float m_run = -1e30f, l_run = 0.f;

  for (int kt = 0; kt < 16; ++kt) {
    int t0 = kt * 64;
    // S^T = K Q^T   (m = t, n = q)
    f32x4 sacc[4] = {};
#pragma unroll
    for (int mf = 0; mf < 4; ++mf) {
      const bf16_t* kp = qkb + (size_t)(t0 + mf * 16 + lr) * C2_ + 64;
      bf16x8 k0 = *(const bf16x8*)(kp + lq * 8);
      bf16x8 k1 = *(const bf16x8*)(kp + 32 + lq * 8);
      sacc[mf] = __builtin_amdgcn_mfma_f32_16x16x32_bf16(k0, qf0, sacc[mf], 0, 0, 0);
      sacc[mf] = __builtin_amdgcn_mfma_f32_16x16x32_bf16(k1, qf1, sacc[mf], 0, 0, 0);
    }
    // online softmax: lane owns row q = qb+lr, 16 t-values local
    float mx = -1e30f;
#pragma unroll
    for (int mf = 0; mf < 4; ++mf)
#pragma unroll
      for (int r = 0; r < 4; ++r) mx = fmaxf(mx, sacc[mf][r]);
    mx = fmaxf(mx, __shfl_xor(mx, 16));
    mx = fmaxf(mx, __shfl_xor(mx, 32));
    float mn = fmaxf(m_run, mx);
    float alpha = __expf(m_run - mn);
    m_run = mn;
    float p[4][4];
    float rs = 0.f;
#pragma unroll
    for (int mf = 0; mf < 4; ++mf)
#pragma unroll
      for (int r = 0; r < 4; ++r) {
        float v = __expf(sacc[mf][r] - mn);
        p[mf][r] = v; rs += v;
      }
    rs += __shfl_xor(rs, 16);
    rs += __shfl_xor(rs, 32);
    l_run = l_run * alpha + rs;
#pragma unroll
    for (int df = 0; df < 4; ++df)
#pragma unroll
      for (int r = 0; r < 4; ++r) oacc[df][r] *= alpha;

    // pack P^T values to bf16 pairs: pk[mf][j] = (p[mf][2j], p[mf][2j+1])
    unsigned pk[4][2];
#pragma unroll
    for (int mf = 0; mf < 4; ++mf)
#pragma unroll
      for (int j = 0; j < 2; ++j) pk[mf][j] = pack2(p[mf][2 * j], p[mf][2 * j + 1]);

    // PV: O^T[d][q] += V^T[d][t] P^T[t][q]
#pragma unroll
    for (int kk = 0; kk < 2; ++kk) {
      u32x4 bw;
#pragma unroll
      for (int w = 0; w < 4; ++w) {
        int src = lr + 16 * (((lq & 1) << 1) + (w >> 1));
        unsigned v0 = (unsigned)__shfl((int)pk[kk * 2 + 0][w & 1], src);
        unsigned v1 = (unsigned)__shfl((int)pk[kk * 2 + 1][w & 1], src);
        bw[w] = (lq & 2) ? v1 : v0;
      }
      bf16x8 pb = __builtin_bit_cast(bf16x8, bw);
#pragma unroll
      for (int df = 0; df < 4; ++df) {
        bf16x8 av = *(const bf16x8*)(vtb + (size_t)(df * 16 + lr) * S_ + t0 + kk * 32 + lq * 8);
        oacc[df] = __builtin_amdgcn_mfma_f32_16x16x32_bf16(av, pb, oacc[df], 0, 0, 0);
      }
    }
  }

  // epilogue: lane holds O^T[d = df*16+lq*4+r][q = qb+lr]
  float inv = 1.f / l_run;
  bf16_t* aop = ao + ((size_t)b * S_ + qb + lr) * C_ + head * HD;
#pragma unroll
  for (int df = 0; df < 4; ++df)
#pragma unroll
    for (int rp = 0; rp < 4; rp += 2) {
      unsigned u = pack2(oacc[df][rp] * inv, oacc[df][rp + 1] * inv);
      *(unsigned*)(aop + df * 16 + lq * 4 + rp) = u;
    }
}

// ---------------------------------------------------------------------------
// Out projection + bias + residual: out[b][d][s] = x + b_out[d] + ao @ WoT
// A = woutt [512][512] (m = d), B = ao [8192][512] (n = (b,s)).
// ---------------------------------------------------------------------------
__global__ __launch_bounds__(256) void gemm_out_kernel(
    const bf16_t* __restrict__ Aw, const bf16_t* __restrict__ Bm,
    const float* __restrict__ bias, const float* __restrict__ xres,
    float* __restrict__ out) {
  int n0 = blockIdx.x * 128;  // (b,s)
  int m0 = blockIdx.y * 128;  // d
  int wave = threadIdx.x >> 6, lane = threadIdx.x & 63;
  int wr = wave >> 1, wc = wave & 1;
  int lr = lane & 15, lq = lane >> 4;
  const bf16_t* Ap = Aw + (size_t)(m0 + wr * 64 + lr) * C_ + lq * 8;
  const bf16_t* Bp = Bm + (size_t)(n0 + wc * 64 + lr) * C_ + lq * 8;
  f32x4 acc[4][4] = {};
#pragma unroll 2
  for (int k0 = 0; k0 < C_; k0 += 32) {
    bf16x8 a[4], bb[4];
#pragma unroll
    for (int i = 0; i < 4; ++i) {
      a[i]  = *(const bf16x8*)(Ap + (size_t)i * 16 * C_ + k0);
      bb[i] = *(const bf16x8*)(Bp + (size_t)i * 16 * C_ + k0);
    }
#pragma unroll
    for (int i = 0; i < 4; ++i)
#pragma unroll
      for (int j = 0; j < 4; ++j)
        acc[i][j] = __builtin_amdgcn_mfma_f32_16x16x32_bf16(a[i], bb[j], acc[i][j], 0, 0, 0);
  }
#pragma unroll
  for (int i = 0; i < 4; ++i) {
#pragma unroll
    for (int j = 0; j < 4; ++j) {
      int n = n0 + wc * 64 + j * 16 + lr;
      int b_ = n >> 10, s = n & 1023;
#pragma unroll
      for (int r = 0; r < 4; ++r) {
        int d = m0 + wr * 64 + i * 16 + lq * 4 + r;
        size_t o = ((size_t)b_ * C_ + d) * S_ + s;
        out[o] = xres[o] + bias[d] + acc[i][j][r];
      }
    }
  }
}

// ---------------------------------------------------------------------------
extern "C" void kernel_launch(void* const* d_in, const int* in_sizes, int n_in,
                              void* d_out, int out_size, void* d_ws, size_t ws_size,
                              hipStream_t stream) {
  const float* x        = (const float*)d_in[0];
  const float* gn_scale = (const float*)d_in[1];
  const float* gn_bias  = (const float*)d_in[2];
  const float* W_qkv    = (const float*)d_in[3];
  const float* b_qkv    = (const float*)d_in[4];
  const float* W_out    = (const float*)d_in[5];
  const float* b_out    = (const float*)d_in[6];
  float* out = (float*)d_out;

  char* ws = (char*)d_ws;
  bf16_t* h_t   = (bf16_t*)(ws);                 // 8 MiB: [b][s][c]
  bf16_t* qk_t  = (bf16_t*)(ws + 8388608);       // 16 MiB: [b][s][h*128+qkdet]
  bf16_t* vt    = (bf16_t*)(ws + 25165824);      // 8 MiB: [b][h][dv][s]
  bf16_t* ao_t  = (bf16_t*)(ws + 33554432);      // 8 MiB: [b][s][c]
  bf16_t* wqkvt = (bf16_t*)(ws + 41943040);      // 1.5 MiB: [1536][512]
  bf16_t* woutt = (bf16_t*)(ws + 43515904);      // 0.5 MiB: [512][512]

  transpose_w_kernel<<<dim3(48, 16), 256, 0, stream>>>(W_qkv, wqkvt, C_, C3_);
  transpose_w_kernel<<<dim3(16, 16), 256, 0, stream>>>(W_out, woutt, C_, C_);
  gn_transpose_kernel<<<256, 256, 0, stream>>>(x, gn_scale, gn_bias, h_t);
  gemm_qkv_kernel<<<dim3(12, 64), 256, 0, stream>>>(h_t, wqkvt, b_qkv, qk_t, vt);
  attn_kernel<<<dim3(16, 8, 8), 256, 0, stream>>>(qk_t, vt, ao_t);
  gemm_out_kernel<<<dim3(64, 4), 256, 0, stream>>>(woutt, ao_t, b_out, x, out);
}

// Round 3
// 116.012 us; speedup vs baseline: 2.5597x; 1.9543x over previous
//
#include <hip/hip_runtime.h>
#include <hip/hip_bf16.h>

typedef __bf16 bf16_t;
typedef __attribute__((ext_vector_type(8))) __bf16 bf16x8;
typedef __attribute__((ext_vector_type(4))) float f32x4;
typedef __attribute__((ext_vector_type(4))) unsigned int u32x4;

#define B_   8
#define C_   512
#define S_   1024
#define NH   8
#define C2_  1024
#define C3_  1536
#define QSCALE 0.1803368801111204f  // 0.125 * log2(e): softmax done in exp2 domain

static __device__ __forceinline__ unsigned pack2(float a, float b) {
  unsigned short lo = __builtin_bit_cast(unsigned short, (bf16_t)a);
  unsigned short hi = __builtin_bit_cast(unsigned short, (bf16_t)b);
  return (unsigned)lo | ((unsigned)hi << 16);
}

static __device__ __forceinline__ void load_lds16(const void* g, void* l) {
  __builtin_amdgcn_global_load_lds(
      (const __attribute__((address_space(1))) unsigned*)g,
      (__attribute__((address_space(3))) unsigned*)l, 16, 0, 0);
}

// Stage ROUNDS*256 16B chunks into LDS. Tile rows are 128B (8 chunks);
// source chunk is XOR-swizzled (c ^ row&7) so ds_read_b128 frags are
// conflict-free while the LDS dest stays linear (guide §5/m173 pattern).
template<int ROUNDS>
static __device__ __forceinline__ void stage_swz(const bf16_t* g, int rstride,
                                                 char* lbuf, int tid) {
#pragma unroll
  for (int r = 0; r < ROUNDS; ++r) {
    int i = r * 256 + tid;
    int row = i >> 3;
    int cg = (i & 7) ^ (row & 7);
    load_lds16(g + (size_t)row * rstride + cg * 8,
               lbuf + r * 4096 + (tid & 192) * 16);  // wave-uniform base
  }
}

// ---------------------------------------------------------------------------
// GroupNorm fused with bf16 cast + transpose: x[b][c][s] f32 -> h_t[b][s][c]
// ---------------------------------------------------------------------------
__global__ __launch_bounds__(256) void gn_transpose_kernel(
    const float* __restrict__ x, const float* __restrict__ scale,
    const float* __restrict__ bias, bf16_t* __restrict__ h_t) {
  int b = blockIdx.x >> 5, g = blockIdx.x & 31;
  int tid = threadIdx.x;
  const float* xb = x + ((size_t)b * C_ + g * 16) * S_;

  float s = 0.f, s2 = 0.f;
  for (int i = tid; i < 16 * S_; i += 256) {
    float v = xb[i];
    s += v; s2 += v * v;
  }
  for (int off = 32; off > 0; off >>= 1) {
    s  += __shfl_down(s, off);
    s2 += __shfl_down(s2, off);
  }
  __shared__ float red[8];
  int wave = tid >> 6, lane = tid & 63;
  if (lane == 0) { red[wave] = s; red[4 + wave] = s2; }
  __syncthreads();
  float ts = red[0] + red[1] + red[2] + red[3];
  float t2 = red[4] + red[5] + red[6] + red[7];
  const float inv_n = 1.f / (16.f * S_);
  float mean = ts * inv_n;
  float var  = t2 * inv_n - mean * mean;
  float rstd = rsqrtf(var + 1e-6f);

  __shared__ bf16_t T[256 * 17];
  for (int chunk = 0; chunk < 4; ++chunk) {
    int s0 = chunk * 256;
    __syncthreads();
    for (int cl = 0; cl < 16; ++cl) {
      float v = xb[cl * S_ + s0 + tid];
      float y = (v - mean) * rstd * scale[g * 16 + cl] + bias[g * 16 + cl];
      T[tid * 17 + cl] = (bf16_t)y;
    }
    __syncthreads();
    int c = tid & 15, sb = tid >> 4;
    for (int j = 0; j < 16; ++j) {
      int sl = sb + j * 16;
      h_t[((size_t)b * S_ + s0 + sl) * C_ + g * 16 + c] = T[sl * 17 + c];
    }
  }
}

// ---------------------------------------------------------------------------
// W_qkv prep: transpose + permute d -> d' = part*512 + h*64 + dq, fold the
// softmax scale (0.125*log2e) into the Q third of W and bias.
// W [512 c][1536 d] f32 -> Wt[d'][c] bf16, bt[d'] f32
// ---------------------------------------------------------------------------
__global__ __launch_bounds__(256) void prep_wqkv_kernel(
    const float* __restrict__ W, const float* __restrict__ bq,
    bf16_t* __restrict__ Wt, float* __restrict__ bt) {
  __shared__ float T[32 * 33];
  int d0 = blockIdx.x * 32, c0 = blockIdx.y * 32;
  int tid = threadIdx.x, ld = tid & 31, lc = tid >> 5;
#pragma unroll
  for (int i = 0; i < 4; ++i) {
    int c = lc + i * 8;
    T[c * 33 + ld] = W[(size_t)(c0 + c) * C3_ + d0 + ld];
  }
  __syncthreads();
#pragma unroll
  for (int i = 0; i < 4; ++i) {
    int dd = lc + i * 8;
    int d = d0 + dd;
    int h = d / 192, rr = d - h * 192, part = rr >> 6, dq = rr & 63;
    float scl = (part == 0) ? QSCALE : 1.f;
    Wt[(size_t)(part * 512 + h * 64 + dq) * C_ + c0 + ld] =
        (bf16_t)(T[ld * 33 + dd] * scl);
  }
  if (blockIdx.y == 0 && tid < 32) {
    int d = d0 + tid;
    int h = d / 192, rr = d - h * 192, part = rr >> 6, dq = rr & 63;
    bt[part * 512 + h * 64 + dq] = bq[d] * ((part == 0) ? QSCALE : 1.f);
  }
}

// Transpose f32 W[R][Ccols] -> bf16 Wt[Ccols][R]  (for W_out)
__global__ __launch_bounds__(256) void transpose_w_kernel(
    const float* __restrict__ W, bf16_t* __restrict__ Wt, int R, int Ccols) {
  __shared__ float T[32 * 33];
  int c0 = blockIdx.x * 32, r0 = blockIdx.y * 32;
  int tid = threadIdx.x;
  int lc = tid & 31, lr = tid >> 5;
  for (int i = 0; i < 4; ++i) {
    int r = lr + i * 8;
    T[r * 33 + lc] = W[(size_t)(r0 + r) * Ccols + c0 + lc];
  }
  __syncthreads();
  for (int i = 0; i < 4; ++i) {
    int cc = lr + i * 8;
    Wt[(size_t)(c0 + cc) * R + r0 + lc] = (bf16_t)T[lc * 33 + cc];
  }
}

// ---------------------------------------------------------------------------
// Shared staged-GEMM mainloop: C[128 m][128 n] = A[m][k] * B[n][k], K=512.
// BK=64, double-buffered global_load_lds staging, counted vmcnt, raw barriers.
// ---------------------------------------------------------------------------
static __device__ __forceinline__ void gemm_loop(
    const bf16_t* Asrc, int Astride, const bf16_t* Bsrc, int Bstride,
    char* lds, int tid, f32x4 (&acc)[4][4]) {
  int wave = tid >> 6, lane = tid & 63;
  int wr = wave >> 1, wc = wave & 1;
  int lr = lane & 15, lq = lane >> 4;
  char* A0 = lds;
  char* B0 = lds + 16384;
  char* A1 = lds + 32768;
  char* B1 = lds + 49152;
  stage_swz<4>(Asrc, Astride, A0, tid);
  stage_swz<4>(Bsrc, Bstride, B0, tid);
#pragma unroll 1
  for (int ks = 0; ks < 8; ++ks) {
    if (ks < 7) {
      stage_swz<4>(Asrc + (ks + 1) * 64, Astride, (ks & 1) ? A0 : A1, tid);
      stage_swz<4>(Bsrc + (ks + 1) * 64, Bstride, (ks & 1) ? B0 : B1, tid);
      asm volatile("s_waitcnt vmcnt(8)" ::: "memory");
    } else {
      asm volatile("s_waitcnt vmcnt(0)" ::: "memory");
    }
    __builtin_amdgcn_s_barrier();
    const char* Ab = (ks & 1) ? A1 : A0;
    const char* Bb = (ks & 1) ? B1 : B0;
#pragma unroll
    for (int kk = 0; kk < 2; ++kk) {
      int co = ((kk * 4 + lq) ^ (lr & 7)) << 4;
      bf16x8 a[4], b[4];
#pragma unroll
      for (int i = 0; i < 4; ++i)
        a[i] = *(const bf16x8*)(Ab + (wr * 64 + i * 16 + lr) * 128 + co);
#pragma unroll
      for (int j = 0; j < 4; ++j)
        b[j] = *(const bf16x8*)(Bb + (wc * 64 + j * 16 + lr) * 128 + co);
#pragma unroll
      for (int i = 0; i < 4; ++i)
#pragma unroll
        for (int j = 0; j < 4; ++j)
          acc[i][j] = __builtin_amdgcn_mfma_f32_16x16x32_bf16(a[i], b[j], acc[i][j], 0, 0, 0);
    }
    __builtin_amdgcn_s_barrier();
  }
}

// ---------------------------------------------------------------------------
// QK projection: C[(b,s)][d'] for d' in [0,1024) -> qk[b][s][h*128+det]
// LDS-bounce epilogue for fully-coalesced b128 stores.
// ---------------------------------------------------------------------------
__global__ __launch_bounds__(256) void gemm_qk_kernel(
    const bf16_t* __restrict__ A, const bf16_t* __restrict__ Bw,
    const float* __restrict__ bias, bf16_t* __restrict__ qk) {
  __shared__ char lds[65536];
  int tid = threadIdx.x;
  int n0 = blockIdx.x * 128, m0 = blockIdx.y * 128;
  f32x4 acc[4][4] = {};
  gemm_loop(A + (size_t)m0 * C_, C_, Bw + (size_t)n0 * C_, C_, lds, tid, acc);
  int wave = tid >> 6, lane = tid & 63;
  int wr = wave >> 1, wc = wave & 1, lr = lane & 15, lq = lane >> 4;
  float bv[4];
#pragma unroll
  for (int j = 0; j < 4; ++j) bv[j] = bias[n0 + wc * 64 + j * 16 + lr];
  unsigned short* tb = (unsigned short*)lds;
#pragma unroll
  for (int i = 0; i < 4; ++i)
#pragma unroll
    for (int j = 0; j < 4; ++j)
#pragma unroll
      for (int r = 0; r < 4; ++r) {
        int row = wr * 64 + i * 16 + lq * 4 + r;
        int col = wc * 64 + j * 16 + lr;
        int byte = row * 256 + (((col >> 3) ^ (row & 7)) << 4) + ((col & 7) << 1);
        tb[byte >> 1] = __builtin_bit_cast(unsigned short, (bf16_t)(acc[i][j][r] + bv[j]));
      }
  __builtin_amdgcn_s_barrier();
#pragma unroll
  for (int u = 0; u < 8; ++u) {
    int flat = tid + u * 256;
    int row = flat >> 4, c = flat & 15;
    u32x4 v = *(const u32x4*)(lds + row * 256 + ((c ^ (row & 7)) << 4));
    int m = m0 + row, b = m >> 10, s = m & 1023;
    int d = n0 + c * 8;
    int h = (d >> 6) & 7, det = ((d >> 9) << 6) + (d & 63);
    *(u32x4*)(qk + ((size_t)(b * S_ + s)) * C2_ + h * 128 + det) = v;
  }
}

// ---------------------------------------------------------------------------
// V projection with swapped operands: C[dv'][(b,s)] -> vt[b][h][dv][s]
// ---------------------------------------------------------------------------
__global__ __launch_bounds__(256) void gemm_v_kernel(
    const bf16_t* __restrict__ Aw, const bf16_t* __restrict__ Bh,
    const float* __restrict__ bias, bf16_t* __restrict__ vt) {
  __shared__ char lds[65536];
  int tid = threadIdx.x;
  int n0 = blockIdx.x * 128, m0 = blockIdx.y * 128;
  f32x4 acc[4][4] = {};
  gemm_loop(Aw + (size_t)m0 * C_, C_, Bh + (size_t)n0 * C_, C_, lds, tid, acc);
  int wave = tid >> 6, lane = tid & 63;
  int wr = wave >> 1, wc = wave & 1, lr = lane & 15, lq = lane >> 4;
  float bv[4][4];
#pragma unroll
  for (int i = 0; i < 4; ++i) {
    f32x4 t = *(const f32x4*)(bias + 1024 + m0 + wr * 64 + i * 16 + lq * 4);
#pragma unroll
    for (int r = 0; r < 4; ++r) bv[i][r] = t[r];
  }
  unsigned short* tb = (unsigned short*)lds;
#pragma unroll
  for (int i = 0; i < 4; ++i)
#pragma unroll
    for (int j = 0; j < 4; ++j)
#pragma unroll
      for (int r = 0; r < 4; ++r) {
        int row = wr * 64 + i * 16 + lq * 4 + r;
        int col = wc * 64 + j * 16 + lr;
        int byte = row * 256 + (((col >> 3) ^ (row & 7)) << 4) + ((col & 7) << 1);
        tb[byte >> 1] = __builtin_bit_cast(unsigned short, (bf16_t)(acc[i][j][r] + bv[i][r]));
      }
  __builtin_amdgcn_s_barrier();
#pragma unroll
  for (int u = 0; u < 8; ++u) {
    int flat = tid + u * 256;
    int row = flat >> 4, c = flat & 15;
    u32x4 v = *(const u32x4*)(lds + row * 256 + ((c ^ (row & 7)) << 4));
    int m = m0 + row;                       // dv'' = h*64+dv
    int h = m >> 6, dv = m & 63;
    int n = n0 + c * 8, b = n >> 10, s = n & 1023;
    *(u32x4*)(vt + ((size_t)((b * NH + h) * 64 + dv)) * S_ + s) = v;
  }
}

// ---------------------------------------------------------------------------
// Flash attention: qk[b][s][h*128+det], vt[b][h][dv][s] -> ao[b][s][c]
// 4 waves x 32 q-rows; K/V LDS-staged (swizzled), triple-buffered with
// counted vmcnt; swapped QK^T; softmax in exp2 domain; in-register P.
// ---------------------------------------------------------------------------
__global__ __launch_bounds__(256) void attn_kernel(
    const bf16_t* __restrict__ qk, const bf16_t* __restrict__ vt,
    bf16_t* __restrict__ ao) {
  __shared__ char lds[49152];
  int qt = blockIdx.x, head = blockIdx.y, b = blockIdx.z;
  int tid = threadIdx.x, wave = tid >> 6, lane = tid & 63;
  int lr = lane & 15, lq = lane >> 4;
  int qb = qt * 128 + wave * 32;
  const bf16_t* qkb = qk + (size_t)b * S_ * C2_ + head * 128;
  const bf16_t* vtb = vt + (size_t)((b * NH + head) * 64) * S_;

  bf16x8 qf[2][2];
#pragma unroll
  for (int q2 = 0; q2 < 2; ++q2)
#pragma unroll
    for (int kk = 0; kk < 2; ++kk)
      qf[q2][kk] = *(const bf16x8*)(qkb + (size_t)(qb + q2 * 16 + lr) * C2_ + kk * 32 + lq * 8);

  f32x4 oacc[2][4] = {};
  float m_run[2] = {-1e30f, -1e30f}, l_run[2] = {0.f, 0.f};

  char* sb0 = lds;
  char* sb1 = lds + 16384;
  char* sb2 = lds + 32768;

#define STAGE_KV(kt, buf)                                                   \
  do {                                                                      \
    stage_swz<2>(qkb + (size_t)((kt) * 64) * C2_ + 64, C2_, (buf), tid);    \
    stage_swz<2>(vtb + (kt) * 64, S_, (buf) + 8192, tid);                   \
  } while (0)

  STAGE_KV(0, sb0);
#pragma unroll 1
  for (int kt = 0; kt < 16; ++kt) {
    if (kt < 15) {
      STAGE_KV(kt + 1, sb1);
      asm volatile("s_waitcnt vmcnt(4)" ::: "memory");
    } else {
      asm volatile("s_waitcnt vmcnt(0)" ::: "memory");
    }
    __builtin_amdgcn_s_barrier();

    // S^T = K Q^T  (log2 domain; Q pre-scaled by 0.125*log2e)
    f32x4 sacc[2][4] = {};
#pragma unroll
    for (int kk = 0; kk < 2; ++kk) {
      int co = ((kk * 4 + lq) ^ (lr & 7)) << 4;
      bf16x8 kf[4];
#pragma unroll
      for (int mf = 0; mf < 4; ++mf)
        kf[mf] = *(const bf16x8*)(sb0 + (mf * 16 + lr) * 128 + co);
#pragma unroll
      for (int q2 = 0; q2 < 2; ++q2)
#pragma unroll
        for (int mf = 0; mf < 4; ++mf)
          sacc[q2][mf] = __builtin_amdgcn_mfma_f32_16x16x32_bf16(kf[mf], qf[q2][kk], sacc[q2][mf], 0, 0, 0);
    }

    // online softmax; lane owns q = qb + q2*16 + lr with 16 local t-values
    unsigned pk[2][4][2];
#pragma unroll
    for (int q2 = 0; q2 < 2; ++q2) {
      float mx = -1e30f;
#pragma unroll
      for (int mf = 0; mf < 4; ++mf)
#pragma unroll
        for (int r = 0; r < 4; ++r) mx = fmaxf(mx, sacc[q2][mf][r]);
      mx = fmaxf(mx, __shfl_xor(mx, 16));
      mx = fmaxf(mx, __shfl_xor(mx, 32));
      float mn = fmaxf(m_run[q2], mx);
      float alpha = __builtin_amdgcn_exp2f(m_run[q2] - mn);
      m_run[q2] = mn;
      float p[4][4];
      float rs = 0.f;
#pragma unroll
      for (int mf = 0; mf < 4; ++mf)
#pragma unroll
        for (int r = 0; r < 4; ++r) {
          float v = __builtin_amdgcn_exp2f(sacc[q2][mf][r] - mn);
          p[mf][r] = v; rs += v;
        }
      rs += __shfl_xor(rs, 16);
      rs += __shfl_xor(rs, 32);
      l_run[q2] = l_run[q2] * alpha + rs;
#pragma unroll
      for (int df = 0; df < 4; ++df)
#pragma unroll
        for (int r = 0; r < 4; ++r) oacc[q2][df][r] *= alpha;
#pragma unroll
      for (int mf = 0; mf < 4; ++mf)
#pragma unroll
        for (int j = 0; j < 2; ++j)
          pk[q2][mf][j] = pack2(p[mf][2 * j], p[mf][2 * j + 1]);
    }

    // O^T += V^T P^T
#pragma unroll
    for (int kk = 0; kk < 2; ++kk) {
      int co = ((kk * 4 + lq) ^ (lr & 7)) << 4;
      bf16x8 vf[4];
#pragma unroll
      for (int df = 0; df < 4; ++df)
        vf[df] = *(const bf16x8*)(sb0 + 8192 + (df * 16 + lr) * 128 + co);
#pragma unroll
      for (int q2 = 0; q2 < 2; ++q2) {
        u32x4 bw;
#pragma unroll
        for (int w = 0; w < 4; ++w) {
          int src = lr + 16 * (((lq & 1) << 1) + (w >> 1));
          unsigned v0 = (unsigned)__shfl((int)pk[q2][kk * 2 + 0][w & 1], src);
          unsigned v1 = (unsigned)__shfl((int)pk[q2][kk * 2 + 1][w & 1], src);
          bw[w] = (lq & 2) ? v1 : v0;
        }
        bf16x8 pb = __builtin_bit_cast(bf16x8, bw);
#pragma unroll
        for (int df = 0; df < 4; ++df)
          oacc[q2][df] = __builtin_amdgcn_mfma_f32_16x16x32_bf16(vf[df], pb, oacc[q2][df], 0, 0, 0);
      }
    }
    char* tp = sb0; sb0 = sb1; sb1 = sb2; sb2 = tp;
  }

  // epilogue: lane holds O^T[d = df*16+lq*4+r][q = qb+q2*16+lr]
#pragma unroll
  for (int q2 = 0; q2 < 2; ++q2) {
    float inv = 1.f / l_run[q2];
    bf16_t* aop = ao + ((size_t)b * S_ + qb + q2 * 16 + lr) * C_ + head * 64;
#pragma unroll
    for (int df = 0; df < 4; ++df)
#pragma unroll
      for (int rp = 0; rp < 4; rp += 2) {
        unsigned u = pack2(oacc[q2][df][rp] * inv, oacc[q2][df][rp + 1] * inv);
        *(unsigned*)(aop + df * 16 + lq * 4 + rp) = u;
      }
  }
#undef STAGE_KV
}

// ---------------------------------------------------------------------------
// Out projection + bias + residual: out[b][d][s] = x + b_out[d] + ao @ W_out
// C[m=(b,s)][n=d]; f32x4 stores (s-contiguous).
// ---------------------------------------------------------------------------
__global__ __launch_bounds__(256) void gemm_out_kernel(
    const bf16_t* __restrict__ A, const bf16_t* __restrict__ Bw,
    const float* __restrict__ bias, const float* __restrict__ xres,
    float* __restrict__ out) {
  __shared__ char lds[65536];
  int tid = threadIdx.x;
  int n0 = blockIdx.x * 128, m0 = blockIdx.y * 128;
  f32x4 acc[4][4] = {};
  gemm_loop(A + (size_t)m0 * C_, C_, Bw + (size_t)n0 * C_, C_, lds, tid, acc);
  int wave = tid >> 6, lane = tid & 63;
  int wr = wave >> 1, wc = wave & 1, lr = lane & 15, lq = lane >> 4;
#pragma unroll
  for (int i = 0; i < 4; ++i) {
#pragma unroll
    for (int j = 0; j < 4; ++j) {
      int d = n0 + wc * 64 + j * 16 + lr;
      int m = m0 + wr * 64 + i * 16 + lq * 4;
      int b = m >> 10, s = m & 1023;
      size_t o = ((size_t)b * C_ + d) * S_ + s;
      f32x4 res = *(const f32x4*)(xres + o);
      f32x4 val;
      float bd = bias[d];
#pragma unroll
      for (int r = 0; r < 4; ++r) val[r] = res[r] + bd + acc[i][j][r];
      *(f32x4*)(out + o) = val;
    }
  }
}

// ---------------------------------------------------------------------------
extern "C" void kernel_launch(void* const* d_in, const int* in_sizes, int n_in,
                              void* d_out, int out_size, void* d_ws, size_t ws_size,
                              hipStream_t stream) {
  const float* x        = (const float*)d_in[0];
  const float* gn_scale = (const float*)d_in[1];
  const float* gn_bias  = (const float*)d_in[2];
  const float* W_qkv    = (const float*)d_in[3];
  const float* b_qkv    = (const float*)d_in[4];
  const float* W_out    = (const float*)d_in[5];
  const float* b_out    = (const float*)d_in[6];
  float* out = (float*)d_out;

  char* ws = (char*)d_ws;
  bf16_t* h_t   = (bf16_t*)(ws);               // 8 MiB  [b][s][c]
  bf16_t* qk_t  = (bf16_t*)(ws + 8388608);     // 16 MiB [b][s][h*128+det]
  bf16_t* vt    = (bf16_t*)(ws + 25165824);    // 8 MiB  [b][h][dv][s]
  bf16_t* ao_t  = (bf16_t*)(ws + 33554432);    // 8 MiB  [b][s][c]
  bf16_t* wqkvp = (bf16_t*)(ws + 41943040);    // 1.5 MiB [d'][c] permuted
  bf16_t* woutt = (bf16_t*)(ws + 43515904);    // 0.5 MiB [d][c]
  // 1536 f32 bias staged at the head of d_out (fully overwritten by gemm_out)
  float* bqp = (float*)d_out;

  prep_wqkv_kernel<<<dim3(48, 16), 256, 0, stream>>>(W_qkv, b_qkv, wqkvp, bqp);
  transpose_w_kernel<<<dim3(16, 16), 256, 0, stream>>>(W_out, woutt, C_, C_);
  gn_transpose_kernel<<<256, 256, 0, stream>>>(x, gn_scale, gn_bias, h_t);
  gemm_qk_kernel<<<dim3(8, 64), 256, 0, stream>>>(h_t, wqkvp, bqp, qk_t);
  gemm_v_kernel<<<dim3(64, 4), 256, 0, stream>>>(wqkvp + 1024 * C_, h_t, bqp, vt);
  attn_kernel<<<dim3(8, 8, 8), 256, 0, stream>>>(qk_t, vt, ao_t);
  gemm_out_kernel<<<dim3(4, 64), 256, 0, stream>>>(ao_t, woutt, b_out, x, out);
}

// Round 4
// 91.275 us; speedup vs baseline: 3.2534x; 1.2710x over previous
//
#include <hip/hip_runtime.h>
#include <hip/hip_bf16.h>

typedef __bf16 bf16_t;
typedef __attribute__((ext_vector_type(8))) __bf16 bf16x8;
typedef __attribute__((ext_vector_type(4))) float f32x4;
typedef __attribute__((ext_vector_type(4))) unsigned int u32x4;

#define B_   8
#define C_   512
#define S_   1024
#define NH   8
#define C2_  1024
#define C3_  1536
#define QSCALE 0.1803368801111204f  // 0.125 * log2(e): softmax in exp2 domain

static __device__ __forceinline__ unsigned pack2(float a, float b) {
  unsigned short lo = __builtin_bit_cast(unsigned short, (bf16_t)a);
  unsigned short hi = __builtin_bit_cast(unsigned short, (bf16_t)b);
  return (unsigned)lo | ((unsigned)hi << 16);
}

static __device__ __forceinline__ void load_lds16(const void* g, void* l) {
  __builtin_amdgcn_global_load_lds(
      (const __attribute__((address_space(1))) unsigned*)g,
      (__attribute__((address_space(3))) unsigned*)l, 16, 0, 0);
}

// Stage ROUNDS*256 16B chunks into LDS. Tile rows are 128B (8 chunks);
// source chunk is XOR-swizzled (c ^ row&7) so ds_read_b128 frags are
// conflict-free while the LDS dest stays linear (m173 pattern).
template<int ROUNDS>
static __device__ __forceinline__ void stage_swz(const bf16_t* g, int rstride,
                                                 char* lbuf, int tid) {
#pragma unroll
  for (int r = 0; r < ROUNDS; ++r) {
    int i = r * 256 + tid;
    int row = i >> 3;
    int cg = (i & 7) ^ (row & 7);
    load_lds16(g + (size_t)row * rstride + cg * 8,
               lbuf + r * 4096 + (tid & 192) * 16);  // wave-uniform base
  }
}

// ---------------------------------------------------------------------------
// Single-pass GroupNorm + bf16 cast + transpose: x[b][c][s] -> h_t[b][s][c]
// x chunk (16ch x 1024s f32 = 64KB) staged in LDS; stats computed on the fly.
// ---------------------------------------------------------------------------
__global__ __launch_bounds__(256) void gn_kernel(
    const float* __restrict__ x, const float* __restrict__ scale,
    const float* __restrict__ bias, bf16_t* __restrict__ h_t) {
  __shared__ float xs[16 * 1024];
  __shared__ float red[8];
  int b = blockIdx.x >> 5, g = blockIdx.x & 31;
  int tid = threadIdx.x;
  const f32x4* xb4 = (const f32x4*)(x + ((size_t)b * C_ + g * 16) * S_);

  float s = 0.f, s2 = 0.f;
#pragma unroll
  for (int k = 0; k < 16; ++k) {
    int vf = k * 256 + tid;
    f32x4 v = xb4[vf];
    ((f32x4*)xs)[vf] = v;
#pragma unroll
    for (int e = 0; e < 4; ++e) { s += v[e]; s2 += v[e] * v[e]; }
  }
  for (int off = 32; off > 0; off >>= 1) {
    s  += __shfl_down(s, off);
    s2 += __shfl_down(s2, off);
  }
  int wave = tid >> 6, lane = tid & 63;
  if (lane == 0) { red[wave] = s; red[4 + wave] = s2; }
  __syncthreads();
  float ts = red[0] + red[1] + red[2] + red[3];
  float t2 = red[4] + red[5] + red[6] + red[7];
  const float inv_n = 1.f / (16.f * S_);
  float mean = ts * inv_n;
  float var  = t2 * inv_n - mean * mean;
  float rstd = rsqrtf(var + 1e-6f);

  float ac[16], bc[16];
#pragma unroll
  for (int cl = 0; cl < 16; ++cl) {
    float sc = scale[g * 16 + cl] * rstd;
    ac[cl] = sc;
    bc[cl] = bias[g * 16 + cl] - mean * sc;
  }
#pragma unroll
  for (int k = 0; k < 4; ++k) {
    int srow = tid + k * 256;
    unsigned ow[8];
#pragma unroll
    for (int p = 0; p < 8; ++p) {
      float y0 = xs[(2 * p    ) * 1024 + srow] * ac[2 * p    ] + bc[2 * p    ];
      float y1 = xs[(2 * p + 1) * 1024 + srow] * ac[2 * p + 1] + bc[2 * p + 1];
      ow[p] = pack2(y0, y1);
    }
    bf16_t* dst = h_t + ((size_t)b * S_ + srow) * C_ + g * 16;
    u32x4 v0, v1;
#pragma unroll
    for (int e = 0; e < 4; ++e) { v0[e] = ow[e]; v1[e] = ow[4 + e]; }
    *(u32x4*)dst = v0;
    *(u32x4*)(dst + 8) = v1;
  }
}

// ---------------------------------------------------------------------------
// W_qkv prep: transpose + permute d -> d' = part*512 + h*64 + dq, fold the
// softmax scale into Q. W [512 c][1536 d] f32 -> Wt[d'][c] bf16, bt[d'] f32
// ---------------------------------------------------------------------------
__global__ __launch_bounds__(256) void prep_wqkv_kernel(
    const float* __restrict__ W, const float* __restrict__ bq,
    bf16_t* __restrict__ Wt, float* __restrict__ bt) {
  __shared__ float T[32 * 33];
  int d0 = blockIdx.x * 32, c0 = blockIdx.y * 32;
  int tid = threadIdx.x, ld = tid & 31, lc = tid >> 5;
#pragma unroll
  for (int i = 0; i < 4; ++i) {
    int c = lc + i * 8;
    T[c * 33 + ld] = W[(size_t)(c0 + c) * C3_ + d0 + ld];
  }
  __syncthreads();
#pragma unroll
  for (int i = 0; i < 4; ++i) {
    int dd = lc + i * 8;
    int d = d0 + dd;
    int h = d / 192, rr = d - h * 192, part = rr >> 6, dq = rr & 63;
    float scl = (part == 0) ? QSCALE : 1.f;
    Wt[(size_t)(part * 512 + h * 64 + dq) * C_ + c0 + ld] =
        (bf16_t)(T[ld * 33 + dd] * scl);
  }
  if (blockIdx.y == 0 && tid < 32) {
    int d = d0 + tid;
    int h = d / 192, rr = d - h * 192, part = rr >> 6, dq = rr & 63;
    bt[part * 512 + h * 64 + dq] = bq[d] * ((part == 0) ? QSCALE : 1.f);
  }
}

// Transpose f32 W[R][Ccols] -> bf16 Wt[Ccols][R]  (for W_out)
__global__ __launch_bounds__(256) void transpose_w_kernel(
    const float* __restrict__ W, bf16_t* __restrict__ Wt, int R, int Ccols) {
  __shared__ float T[32 * 33];
  int c0 = blockIdx.x * 32, r0 = blockIdx.y * 32;
  int tid = threadIdx.x;
  int lc = tid & 31, lr = tid >> 5;
  for (int i = 0; i < 4; ++i) {
    int r = lr + i * 8;
    T[r * 33 + lc] = W[(size_t)(r0 + r) * Ccols + c0 + lc];
  }
  __syncthreads();
  for (int i = 0; i < 4; ++i) {
    int cc = lr + i * 8;
    Wt[(size_t)(c0 + cc) * R + r0 + lc] = (bf16_t)T[lc * 33 + cc];
  }
}

// ---------------------------------------------------------------------------
// Shared staged-GEMM mainloop: C[128 m][128 n] = A[m][k] * B[n][k], K=512.
// BK=64, double-buffered global_load_lds staging, counted vmcnt, raw barriers.
// ---------------------------------------------------------------------------
static __device__ __forceinline__ void gemm_loop(
    const bf16_t* Asrc, int Astride, const bf16_t* Bsrc, int Bstride,
    char* lds, int tid, f32x4 (&acc)[4][4]) {
  int wave = tid >> 6, lane = tid & 63;
  int wr = wave >> 1, wc = wave & 1;
  int lr = lane & 15, lq = lane >> 4;
  char* A0 = lds;
  char* B0 = lds + 16384;
  char* A1 = lds + 32768;
  char* B1 = lds + 49152;
  stage_swz<4>(Asrc, Astride, A0, tid);
  stage_swz<4>(Bsrc, Bstride, B0, tid);
#pragma unroll 1
  for (int ks = 0; ks < 8; ++ks) {
    if (ks < 7) {
      stage_swz<4>(Asrc + (ks + 1) * 64, Astride, (ks & 1) ? A0 : A1, tid);
      stage_swz<4>(Bsrc + (ks + 1) * 64, Bstride, (ks & 1) ? B0 : B1, tid);
      asm volatile("s_waitcnt vmcnt(8)" ::: "memory");
    } else {
      asm volatile("s_waitcnt vmcnt(0)" ::: "memory");
    }
    __builtin_amdgcn_s_barrier();
    const char* Ab = (ks & 1) ? A1 : A0;
    const char* Bb = (ks & 1) ? B1 : B0;
#pragma unroll
    for (int kk = 0; kk < 2; ++kk) {
      int co = ((kk * 4 + lq) ^ (lr & 7)) << 4;
      bf16x8 a[4], b[4];
#pragma unroll
      for (int i = 0; i < 4; ++i)
        a[i] = *(const bf16x8*)(Ab + (wr * 64 + i * 16 + lr) * 128 + co);
#pragma unroll
      for (int j = 0; j < 4; ++j)
        b[j] = *(const bf16x8*)(Bb + (wc * 64 + j * 16 + lr) * 128 + co);
#pragma unroll
      for (int i = 0; i < 4; ++i)
#pragma unroll
        for (int j = 0; j < 4; ++j)
          acc[i][j] = __builtin_amdgcn_mfma_f32_16x16x32_bf16(a[i], b[j], acc[i][j], 0, 0, 0);
    }
    __builtin_amdgcn_s_barrier();
  }
}

// ---------------------------------------------------------------------------
// Merged QKV projection. 1-D grid, 768 blocks, XCD-grouped so all blocks
// touching one h_t panel land on the same XCD (panel p -> XCD p%8).
//  bid < 512 : QK role. m = (b,s) tile (bid&63), n = d' tile (bid>>6).
//              -> qk[b][s][h*128+det] via LDS-bounce coalesced stores.
//  bid >= 512: V role (swapped operands). m = dv tile, n = (b,s) tile.
//              -> vt[b][h][dv][s].
// ---------------------------------------------------------------------------
__global__ __launch_bounds__(256) void gemm_qkv_kernel(
    const bf16_t* __restrict__ h, const bf16_t* __restrict__ wq,
    const float* __restrict__ bias, bf16_t* __restrict__ qk,
    bf16_t* __restrict__ vt) {
  __shared__ char lds[65536];
  int tid = threadIdx.x;
  int bid = blockIdx.x;
  int wave = tid >> 6, lane = tid & 63;
  int wr = wave >> 1, wc = wave & 1, lr = lane & 15, lq = lane >> 4;
  unsigned short* tb = (unsigned short*)lds;
  if (bid < 512) {
    int m0 = (bid & 63) * 128, n0 = (bid >> 6) * 128;
    f32x4 acc[4][4] = {};
    gemm_loop(h + (size_t)m0 * C_, C_, wq + (size_t)n0 * C_, C_, lds, tid, acc);
    float bv[4];
#pragma unroll
    for (int j = 0; j < 4; ++j) bv[j] = bias[n0 + wc * 64 + j * 16 + lr];
#pragma unroll
    for (int i = 0; i < 4; ++i)
#pragma unroll
      for (int j = 0; j < 4; ++j)
#pragma unroll
        for (int r = 0; r < 4; ++r) {
          int row = wr * 64 + i * 16 + lq * 4 + r;
          int col = wc * 64 + j * 16 + lr;
          int byte = row * 256 + (((col >> 3) ^ (row & 7)) << 4) + ((col & 7) << 1);
          tb[byte >> 1] = __builtin_bit_cast(unsigned short, (bf16_t)(acc[i][j][r] + bv[j]));
        }
    __builtin_amdgcn_s_barrier();
#pragma unroll
    for (int u = 0; u < 8; ++u) {
      int flat = tid + u * 256;
      int row = flat >> 4, c = flat & 15;
      u32x4 v = *(const u32x4*)(lds + row * 256 + ((c ^ (row & 7)) << 4));
      int m = m0 + row, b = m >> 10, s = m & 1023;
      int d = n0 + c * 8;
      int hh = (d >> 6) & 7, det = ((d >> 9) << 6) + (d & 63);
      *(u32x4*)(qk + ((size_t)(b * S_ + s)) * C2_ + hh * 128 + det) = v;
    }
  } else {
    int j2 = bid - 512;
    int n0 = (j2 & 63) * 128, m0 = (j2 >> 6) * 128;
    f32x4 acc[4][4] = {};
    gemm_loop(wq + (size_t)(1024 + m0) * C_, C_, h + (size_t)n0 * C_, C_, lds, tid, acc);
    float bv[4][4];
#pragma unroll
    for (int i = 0; i < 4; ++i) {
      f32x4 t = *(const f32x4*)(bias + 1024 + m0 + wr * 64 + i * 16 + lq * 4);
#pragma unroll
      for (int r = 0; r < 4; ++r) bv[i][r] = t[r];
    }
#pragma unroll
    for (int i = 0; i < 4; ++i)
#pragma unroll
      for (int j = 0; j < 4; ++j)
#pragma unroll
        for (int r = 0; r < 4; ++r) {
          int row = wr * 64 + i * 16 + lq * 4 + r;
          int col = wc * 64 + j * 16 + lr;
          int byte = row * 256 + (((col >> 3) ^ (row & 7)) << 4) + ((col & 7) << 1);
          tb[byte >> 1] = __builtin_bit_cast(unsigned short, (bf16_t)(acc[i][j][r] + bv[i][r]));
        }
    __builtin_amdgcn_s_barrier();
#pragma unroll
    for (int u = 0; u < 8; ++u) {
      int flat = tid + u * 256;
      int row = flat >> 4, c = flat & 15;
      u32x4 v = *(const u32x4*)(lds + row * 256 + ((c ^ (row & 7)) << 4));
      int m = m0 + row;  // h*64+dv
      int hh = m >> 6, dv = m & 63;
      int n = n0 + c * 8, b = n >> 10, s = n & 1023;
      *(u32x4*)(vt + ((size_t)((b * NH + hh) * 64 + dv)) * S_ + s) = v;
    }
  }
}

// ---------------------------------------------------------------------------
// Flash attention. 1-D grid 512, bid = qt*64 + (b*8+head) so all 8 q-tiles
// of one (b,head) share an XCD (K/V L2-resident). 4 waves x 32 q-rows.
// K/V LDS-staged (swizzled), triple-buffered, counted vmcnt; swapped QK^T;
// softmax exp2-domain; P redistributed via permlane32/16_swap (no LDS, no
// bpermute); s_setprio around MFMA clusters.
// ---------------------------------------------------------------------------
__global__ __launch_bounds__(256) void attn_kernel(
    const bf16_t* __restrict__ qk, const bf16_t* __restrict__ vt,
    bf16_t* __restrict__ ao) {
  __shared__ char lds[49152];
  int bid = blockIdx.x;
  int qt = bid >> 6, g = bid & 63;
  int b = g >> 3, head = g & 7;
  int tid = threadIdx.x, wave = tid >> 6, lane = tid & 63;
  int lr = lane & 15, lq = lane >> 4;
  int qb = qt * 128 + wave * 32;
  const bf16_t* qkb = qk + (size_t)b * S_ * C2_ + head * 128;
  const bf16_t* vtb = vt + (size_t)((b * NH + head) * 64) * S_;

  bf16x8 qf[2][2];
#pragma unroll
  for (int q2 = 0; q2 < 2; ++q2)
#pragma unroll
    for (int kk = 0; kk < 2; ++kk)
      qf[q2][kk] = *(const bf16x8*)(qkb + (size_t)(qb + q2 * 16 + lr) * C2_ + kk * 32 + lq * 8);

  f32x4 oacc[2][4] = {};
  float m_run[2] = {-1e30f, -1e30f}, l_run[2] = {0.f, 0.f};

  char* sb0 = lds;
  char* sb1 = lds + 16384;
  char* sb2 = lds + 32768;

#define STAGE_KV(kt, buf)                                                   \
  do {                                                                      \
    stage_swz<2>(qkb + (size_t)((kt) * 64) * C2_ + 64, C2_, (buf), tid);    \
    stage_swz<2>(vtb + (kt) * 64, S_, (buf) + 8192, tid);                   \
  } while (0)

  STAGE_KV(0, sb0);
#pragma unroll 1
  for (int kt = 0; kt < 16; ++kt) {
    if (kt < 15) {
      STAGE_KV(kt + 1, sb1);
      asm volatile("s_waitcnt vmcnt(4)" ::: "memory");
    } else {
      asm volatile("s_waitcnt vmcnt(0)" ::: "memory");
    }
    __builtin_amdgcn_s_barrier();

    // S^T = K Q^T  (Q pre-scaled by 0.125*log2e)
    f32x4 sacc[2][4] = {};
    __builtin_amdgcn_s_setprio(1);
#pragma unroll
    for (int kk = 0; kk < 2; ++kk) {
      int co = ((kk * 4 + lq) ^ (lr & 7)) << 4;
      bf16x8 kf[4];
#pragma unroll
      for (int mf = 0; mf < 4; ++mf)
        kf[mf] = *(const bf16x8*)(sb0 + (mf * 16 + lr) * 128 + co);
#pragma unroll
      for (int q2 = 0; q2 < 2; ++q2)
#pragma unroll
        for (int mf = 0; mf < 4; ++mf)
          sacc[q2][mf] = __builtin_amdgcn_mfma_f32_16x16x32_bf16(kf[mf], qf[q2][kk], sacc[q2][mf], 0, 0, 0);
    }
    __builtin_amdgcn_s_setprio(0);

    // online softmax; lane owns q = qb + q2*16 + lr, 16 local t-values
    unsigned pk[2][4][2];
#pragma unroll
    for (int q2 = 0; q2 < 2; ++q2) {
      float mx = -1e30f;
#pragma unroll
      for (int mf = 0; mf < 4; ++mf)
#pragma unroll
        for (int r = 0; r < 4; ++r) mx = fmaxf(mx, sacc[q2][mf][r]);
      mx = fmaxf(mx, __shfl_xor(mx, 16));
      mx = fmaxf(mx, __shfl_xor(mx, 32));
      float mn = fmaxf(m_run[q2], mx);
      float alpha = __builtin_amdgcn_exp2f(m_run[q2] - mn);
      m_run[q2] = mn;
      float p[4][4];
      float rs = 0.f;
#pragma unroll
      for (int mf = 0; mf < 4; ++mf)
#pragma unroll
        for (int r = 0; r < 4; ++r) {
          float v = __builtin_amdgcn_exp2f(sacc[q2][mf][r] - mn);
          p[mf][r] = v; rs += v;
        }
      rs += __shfl_xor(rs, 16);
      rs += __shfl_xor(rs, 32);
      l_run[q2] = l_run[q2] * alpha + rs;
#pragma unroll
      for (int df = 0; df < 4; ++df)
#pragma unroll
        for (int r = 0; r < 4; ++r) oacc[q2][df][r] *= alpha;
#pragma unroll
      for (int mf = 0; mf < 4; ++mf)
#pragma unroll
        for (int j = 0; j < 2; ++j)
          pk[q2][mf][j] = pack2(p[mf][2 * j], p[mf][2 * j + 1]);
    }

    // O^T += V^T P^T ; P B-frags built with permlane32+permlane16 swaps:
    // p32(u,r) -> {u_lo,r_lo},{u_hi,r_hi}; p16 -> w01, w23 words directly.
#pragma unroll
    for (int kk = 0; kk < 2; ++kk) {
      int co = ((kk * 4 + lq) ^ (lr & 7)) << 4;
      bf16x8 vf[4];
#pragma unroll
      for (int df = 0; df < 4; ++df)
        vf[df] = *(const bf16x8*)(sb0 + 8192 + (df * 16 + lr) * 128 + co);
#pragma unroll
      for (int q2 = 0; q2 < 2; ++q2) {
        unsigned w0 = pk[q2][2 * kk + 0][0], w2 = pk[q2][2 * kk + 1][0];
        unsigned w1 = pk[q2][2 * kk + 0][1], w3 = pk[q2][2 * kk + 1][1];
        asm("v_permlane32_swap_b32 %0, %1" : "+v"(w0), "+v"(w2));
        asm("v_permlane16_swap_b32 %0, %1" : "+v"(w0), "+v"(w2));
        asm("v_permlane32_swap_b32 %0, %1" : "+v"(w1), "+v"(w3));
        asm("v_permlane16_swap_b32 %0, %1" : "+v"(w1), "+v"(w3));
        u32x4 bw; bw[0] = w0; bw[1] = w1; bw[2] = w2; bw[3] = w3;
        bf16x8 pb = __builtin_bit_cast(bf16x8, bw);
        __builtin_amdgcn_s_setprio(1);
#pragma unroll
        for (int df = 0; df < 4; ++df)
          oacc[q2][df] = __builtin_amdgcn_mfma_f32_16x16x32_bf16(vf[df], pb, oacc[q2][df], 0, 0, 0);
        __builtin_amdgcn_s_setprio(0);
      }
    }
    char* tp = sb0; sb0 = sb1; sb1 = sb2; sb2 = tp;
  }

  // epilogue: lane holds O^T[d = df*16+lq*4+r][q = qb+q2*16+lr]
#pragma unroll
  for (int q2 = 0; q2 < 2; ++q2) {
    float inv = 1.f / l_run[q2];
    bf16_t* aop = ao + ((size_t)b * S_ + qb + q2 * 16 + lr) * C_ + head * 64;
#pragma unroll
    for (int df = 0; df < 4; ++df)
#pragma unroll
      for (int rp = 0; rp < 4; rp += 2) {
        unsigned u = pack2(oacc[q2][df][rp] * inv, oacc[q2][df][rp + 1] * inv);
        *(unsigned*)(aop + df * 16 + lq * 4 + rp) = u;
      }
  }
#undef STAGE_KV
}

// ---------------------------------------------------------------------------
// Out projection + bias + residual: out[b][d][s] = x + b_out[d] + ao @ W_out
// 1-D grid 256, bid = ny*64 + mx (same-ao-panel blocks share an XCD).
// ---------------------------------------------------------------------------
__global__ __launch_bounds__(256) void gemm_out_kernel(
    const bf16_t* __restrict__ A, const bf16_t* __restrict__ Bw,
    const float* __restrict__ bias, const float* __restrict__ xres,
    float* __restrict__ out) {
  __shared__ char lds[65536];
  int tid = threadIdx.x;
  int bid = blockIdx.x;
  int m0 = (bid & 63) * 128, n0 = (bid >> 6) * 128;
  f32x4 acc[4][4] = {};
  gemm_loop(A + (size_t)m0 * C_, C_, Bw + (size_t)n0 * C_, C_, lds, tid, acc);
  int wave = tid >> 6, lane = tid & 63;
  int wr = wave >> 1, wc = wave & 1, lr = lane & 15, lq = lane >> 4;
#pragma unroll
  for (int i = 0; i < 4; ++i) {
#pragma unroll
    for (int j = 0; j < 4; ++j) {
      int d = n0 + wc * 64 + j * 16 + lr;
      int m = m0 + wr * 64 + i * 16 + lq * 4;
      int b = m >> 10, s = m & 1023;
      size_t o = ((size_t)b * C_ + d) * S_ + s;
      f32x4 res = *(const f32x4*)(xres + o);
      f32x4 val;
      float bd = bias[d];
#pragma unroll
      for (int r = 0; r < 4; ++r) val[r] = res[r] + bd + acc[i][j][r];
      *(f32x4*)(out + o) = val;
    }
  }
}

// ---------------------------------------------------------------------------
extern "C" void kernel_launch(void* const* d_in, const int* in_sizes, int n_in,
                              void* d_out, int out_size, void* d_ws, size_t ws_size,
                              hipStream_t stream) {
  const float* x        = (const float*)d_in[0];
  const float* gn_scale = (const float*)d_in[1];
  const float* gn_bias  = (const float*)d_in[2];
  const float* W_qkv    = (const float*)d_in[3];
  const float* b_qkv    = (const float*)d_in[4];
  const float* W_out    = (const float*)d_in[5];
  const float* b_out    = (const float*)d_in[6];
  float* out = (float*)d_out;

  char* ws = (char*)d_ws;
  bf16_t* h_t   = (bf16_t*)(ws);               // 8 MiB  [b][s][c]
  bf16_t* qk_t  = (bf16_t*)(ws + 8388608);     // 16 MiB [b][s][h*128+det]
  bf16_t* vt    = (bf16_t*)(ws + 25165824);    // 8 MiB  [b][h][dv][s]
  bf16_t* ao_t  = (bf16_t*)(ws + 33554432);    // 8 MiB  [b][s][c]
  bf16_t* wqkvp = (bf16_t*)(ws + 41943040);    // 1.5 MiB [d'][c] permuted
  bf16_t* woutt = (bf16_t*)(ws + 43515904);    // 0.5 MiB [d][c]
  float* bqp = (float*)d_out;  // 1536 f32 bias, overwritten later by gemm_out

  prep_wqkv_kernel<<<dim3(48, 16), 256, 0, stream>>>(W_qkv, b_qkv, wqkvp, bqp);
  transpose_w_kernel<<<dim3(16, 16), 256, 0, stream>>>(W_out, woutt, C_, C_);
  gn_kernel<<<256, 256, 0, stream>>>(x, gn_scale, gn_bias, h_t);
  gemm_qkv_kernel<<<768, 256, 0, stream>>>(h_t, wqkvp, bqp, qk_t, vt);
  attn_kernel<<<512, 256, 0, stream>>>(qk_t, vt, ao_t);
  gemm_out_kernel<<<256, 256, 0, stream>>>(ao_t, woutt, b_out, x, out);
}

// Round 5
// 82.215 us; speedup vs baseline: 3.6119x; 1.1102x over previous
//
#include <hip/hip_runtime.h>
#include <hip/hip_bf16.h>

typedef __bf16 bf16_t;
typedef __attribute__((ext_vector_type(8))) __bf16 bf16x8;
typedef __attribute__((ext_vector_type(4))) float f32x4;
typedef __attribute__((ext_vector_type(4))) unsigned int u32x4;

#define B_   8
#define C_   512
#define S_   1024
#define NH   8
#define C2_  1024
#define C3_  1536
#define QSCALE 0.1803368801111204f  // 0.125 * log2(e): softmax in exp2 domain

static __device__ __forceinline__ unsigned pack2(float a, float b) {
  unsigned short lo = __builtin_bit_cast(unsigned short, (bf16_t)a);
  unsigned short hi = __builtin_bit_cast(unsigned short, (bf16_t)b);
  return (unsigned)lo | ((unsigned)hi << 16);
}

static __device__ __forceinline__ void load_lds16(const void* g, void* l) {
  __builtin_amdgcn_global_load_lds(
      (const __attribute__((address_space(1))) unsigned*)g,
      (__attribute__((address_space(3))) unsigned*)l, 16, 0, 0);
}

// Stage ROUNDS*256 16B chunks into LDS (256-thread blocks). Rows are 128B
// (8 chunks); source chunk XOR-swizzled (c ^ row&7) so ds_read_b128 frags
// are conflict-free while the LDS dest stays linear (m173 pattern).
template<int ROUNDS>
static __device__ __forceinline__ void stage_swz(const bf16_t* g, int rstride,
                                                 char* lbuf, int tid) {
#pragma unroll
  for (int r = 0; r < ROUNDS; ++r) {
    int i = r * 256 + tid;
    int row = i >> 3;
    int cg = (i & 7) ^ (row & 7);
    load_lds16(g + (size_t)row * rstride + cg * 8,
               lbuf + r * 4096 + (tid & 192) * 16);  // wave-uniform base
  }
}

// 512-thread variant: one round covers 512 chunks = 64 rows = 8 KB.
static __device__ __forceinline__ void stage_swz512(const bf16_t* g, int rstride,
                                                    char* lbuf, int tid) {
  int row = tid >> 3;
  int cg = (tid & 7) ^ (row & 7);
  load_lds16(g + (size_t)row * rstride + cg * 8,
             lbuf + (tid & 448) * 16);  // wave-uniform base
}

// ---------------------------------------------------------------------------
// Single-pass GroupNorm + bf16 cast + transpose: x[b][c][s] -> h_t[b][s][c]
// ---------------------------------------------------------------------------
__global__ __launch_bounds__(256) void gn_kernel(
    const float* __restrict__ x, const float* __restrict__ scale,
    const float* __restrict__ bias, bf16_t* __restrict__ h_t) {
  __shared__ float xs[16 * 1024];
  __shared__ float red[8];
  int b = blockIdx.x >> 5, g = blockIdx.x & 31;
  int tid = threadIdx.x;
  const f32x4* xb4 = (const f32x4*)(x + ((size_t)b * C_ + g * 16) * S_);

  float s = 0.f, s2 = 0.f;
#pragma unroll
  for (int k = 0; k < 16; ++k) {
    int vf = k * 256 + tid;
    f32x4 v = xb4[vf];
    ((f32x4*)xs)[vf] = v;
#pragma unroll
    for (int e = 0; e < 4; ++e) { s += v[e]; s2 += v[e] * v[e]; }
  }
  for (int off = 32; off > 0; off >>= 1) {
    s  += __shfl_down(s, off);
    s2 += __shfl_down(s2, off);
  }
  int wave = tid >> 6, lane = tid & 63;
  if (lane == 0) { red[wave] = s; red[4 + wave] = s2; }
  __syncthreads();
  float ts = red[0] + red[1] + red[2] + red[3];
  float t2 = red[4] + red[5] + red[6] + red[7];
  const float inv_n = 1.f / (16.f * S_);
  float mean = ts * inv_n;
  float var  = t2 * inv_n - mean * mean;
  float rstd = rsqrtf(var + 1e-6f);

  float ac[16], bc[16];
#pragma unroll
  for (int cl = 0; cl < 16; ++cl) {
    float sc = scale[g * 16 + cl] * rstd;
    ac[cl] = sc;
    bc[cl] = bias[g * 16 + cl] - mean * sc;
  }
#pragma unroll
  for (int k = 0; k < 4; ++k) {
    int srow = tid + k * 256;
    unsigned ow[8];
#pragma unroll
    for (int p = 0; p < 8; ++p) {
      float y0 = xs[(2 * p    ) * 1024 + srow] * ac[2 * p    ] + bc[2 * p    ];
      float y1 = xs[(2 * p + 1) * 1024 + srow] * ac[2 * p + 1] + bc[2 * p + 1];
      ow[p] = pack2(y0, y1);
    }
    bf16_t* dst = h_t + ((size_t)b * S_ + srow) * C_ + g * 16;
    u32x4 v0, v1;
#pragma unroll
    for (int e = 0; e < 4; ++e) { v0[e] = ow[e]; v1[e] = ow[4 + e]; }
    *(u32x4*)dst = v0;
    *(u32x4*)(dst + 8) = v1;
  }
}

// ---------------------------------------------------------------------------
// W_qkv prep: transpose + permute d -> d' = part*512 + h*64 + dq, fold the
// softmax scale into Q. W [512 c][1536 d] f32 -> Wt[d'][c] bf16, bt[d'] f32
// ---------------------------------------------------------------------------
__global__ __launch_bounds__(256) void prep_wqkv_kernel(
    const float* __restrict__ W, const float* __restrict__ bq,
    bf16_t* __restrict__ Wt, float* __restrict__ bt) {
  __shared__ float T[32 * 33];
  int d0 = blockIdx.x * 32, c0 = blockIdx.y * 32;
  int tid = threadIdx.x, ld = tid & 31, lc = tid >> 5;
#pragma unroll
  for (int i = 0; i < 4; ++i) {
    int c = lc + i * 8;
    T[c * 33 + ld] = W[(size_t)(c0 + c) * C3_ + d0 + ld];
  }
  __syncthreads();
#pragma unroll
  for (int i = 0; i < 4; ++i) {
    int dd = lc + i * 8;
    int d = d0 + dd;
    int h = d / 192, rr = d - h * 192, part = rr >> 6, dq = rr & 63;
    float scl = (part == 0) ? QSCALE : 1.f;
    Wt[(size_t)(part * 512 + h * 64 + dq) * C_ + c0 + ld] =
        (bf16_t)(T[ld * 33 + dd] * scl);
  }
  if (blockIdx.y == 0 && tid < 32) {
    int d = d0 + tid;
    int h = d / 192, rr = d - h * 192, part = rr >> 6, dq = rr & 63;
    bt[part * 512 + h * 64 + dq] = bq[d] * ((part == 0) ? QSCALE : 1.f);
  }
}

// Transpose f32 W[R][Ccols] -> bf16 Wt[Ccols][R]  (for W_out)
__global__ __launch_bounds__(256) void transpose_w_kernel(
    const float* __restrict__ W, bf16_t* __restrict__ Wt, int R, int Ccols) {
  __shared__ float T[32 * 33];
  int c0 = blockIdx.x * 32, r0 = blockIdx.y * 32;
  int tid = threadIdx.x;
  int lc = tid & 31, lr = tid >> 5;
  for (int i = 0; i < 4; ++i) {
    int r = lr + i * 8;
    T[r * 33 + lc] = W[(size_t)(r0 + r) * Ccols + c0 + lc];
  }
  __syncthreads();
  for (int i = 0; i < 4; ++i) {
    int cc = lr + i * 8;
    Wt[(size_t)(c0 + cc) * R + r0 + lc] = (bf16_t)T[lc * 33 + cc];
  }
}

// ---------------------------------------------------------------------------
// Templated staged-GEMM mainloop: C[MF*32 m][NF*32 n] = A[m][k]*B[n][k], K=512.
// BK=64, double-buffered global_load_lds staging, counted vmcnt, raw barriers.
// 256 threads as 2x2 waves; per wave MF x NF 16x16 frags.
// ---------------------------------------------------------------------------
template<int MF, int NF>
static __device__ __forceinline__ void gemm_loop(
    const bf16_t* Asrc, int Astride, const bf16_t* Bsrc, int Bstride,
    char* lds, int tid, f32x4 (&acc)[MF][NF]) {
  int wave = tid >> 6, lane = tid & 63;
  int wr = wave >> 1, wc = wave & 1;
  int lr = lane & 15, lq = lane >> 4;
  char* A0 = lds;
  char* B0 = lds + MF * 4096;
  char* A1 = lds + (MF + NF) * 4096;
  char* B1 = lds + (2 * MF + NF) * 4096;
  stage_swz<MF>(Asrc, Astride, A0, tid);
  stage_swz<NF>(Bsrc, Bstride, B0, tid);
#pragma unroll 1
  for (int ks = 0; ks < 8; ++ks) {
    if (ks < 7) {
      stage_swz<MF>(Asrc + (ks + 1) * 64, Astride, (ks & 1) ? A0 : A1, tid);
      stage_swz<NF>(Bsrc + (ks + 1) * 64, Bstride, (ks & 1) ? B0 : B1, tid);
      asm volatile("s_waitcnt vmcnt(%0)" :: "i"(MF + NF) : "memory");
    } else {
      asm volatile("s_waitcnt vmcnt(0)" ::: "memory");
    }
    __builtin_amdgcn_s_barrier();
    const char* Ab = (ks & 1) ? A1 : A0;
    const char* Bb = (ks & 1) ? B1 : B0;
#pragma unroll
    for (int kk = 0; kk < 2; ++kk) {
      int co = ((kk * 4 + lq) ^ (lr & 7)) << 4;
      bf16x8 a[MF], b[NF];
#pragma unroll
      for (int i = 0; i < MF; ++i)
        a[i] = *(const bf16x8*)(Ab + (wr * MF * 16 + i * 16 + lr) * 128 + co);
#pragma unroll
      for (int j = 0; j < NF; ++j)
        b[j] = *(const bf16x8*)(Bb + (wc * NF * 16 + j * 16 + lr) * 128 + co);
#pragma unroll
      for (int i = 0; i < MF; ++i)
#pragma unroll
        for (int j = 0; j < NF; ++j)
          acc[i][j] = __builtin_amdgcn_mfma_f32_16x16x32_bf16(a[i], b[j], acc[i][j], 0, 0, 0);
    }
    __builtin_amdgcn_s_barrier();
  }
}

// ---------------------------------------------------------------------------
// Merged QKV projection. 1-D grid, 768 blocks, XCD-grouped (same h_t panel
// -> same XCD). bid<512: QK role -> qk[b][s][h*128+det]; else V role
// (swapped operands) -> vt[b][h][dv][s].
// ---------------------------------------------------------------------------
__global__ __launch_bounds__(256) void gemm_qkv_kernel(
    const bf16_t* __restrict__ h, const bf16_t* __restrict__ wq,
    const float* __restrict__ bias, bf16_t* __restrict__ qk,
    bf16_t* __restrict__ vt) {
  __shared__ char lds[65536];
  int tid = threadIdx.x;
  int bid = blockIdx.x;
  int wave = tid >> 6, lane = tid & 63;
  int wr = wave >> 1, wc = wave & 1, lr = lane & 15, lq = lane >> 4;
  unsigned short* tb = (unsigned short*)lds;
  if (bid < 512) {
    int m0 = (bid & 63) * 128, n0 = (bid >> 6) * 128;
    f32x4 acc[4][4] = {};
    gemm_loop<4, 4>(h + (size_t)m0 * C_, C_, wq + (size_t)n0 * C_, C_, lds, tid, acc);
    float bv[4];
#pragma unroll
    for (int j = 0; j < 4; ++j) bv[j] = bias[n0 + wc * 64 + j * 16 + lr];
#pragma unroll
    for (int i = 0; i < 4; ++i)
#pragma unroll
      for (int j = 0; j < 4; ++j)
#pragma unroll
        for (int r = 0; r < 4; ++r) {
          int row = wr * 64 + i * 16 + lq * 4 + r;
          int col = wc * 64 + j * 16 + lr;
          int byte = row * 256 + (((col >> 3) ^ (row & 7)) << 4) + ((col & 7) << 1);
          tb[byte >> 1] = __builtin_bit_cast(unsigned short, (bf16_t)(acc[i][j][r] + bv[j]));
        }
    __builtin_amdgcn_s_barrier();
#pragma unroll
    for (int u = 0; u < 8; ++u) {
      int flat = tid + u * 256;
      int row = flat >> 4, c = flat & 15;
      u32x4 v = *(const u32x4*)(lds + row * 256 + ((c ^ (row & 7)) << 4));
      int m = m0 + row, b = m >> 10, s = m & 1023;
      int d = n0 + c * 8;
      int hh = (d >> 6) & 7, det = ((d >> 9) << 6) + (d & 63);
      *(u32x4*)(qk + ((size_t)(b * S_ + s)) * C2_ + hh * 128 + det) = v;
    }
  } else {
    int j2 = bid - 512;
    int n0 = (j2 & 63) * 128, m0 = (j2 >> 6) * 128;
    f32x4 acc[4][4] = {};
    gemm_loop<4, 4>(wq + (size_t)(1024 + m0) * C_, C_, h + (size_t)n0 * C_, C_, lds, tid, acc);
    float bv[4][4];
#pragma unroll
    for (int i = 0; i < 4; ++i) {
      f32x4 t = *(const f32x4*)(bias + 1024 + m0 + wr * 64 + i * 16 + lq * 4);
#pragma unroll
      for (int r = 0; r < 4; ++r) bv[i][r] = t[r];
    }
#pragma unroll
    for (int i = 0; i < 4; ++i)
#pragma unroll
      for (int j = 0; j < 4; ++j)
#pragma unroll
        for (int r = 0; r < 4; ++r) {
          int row = wr * 64 + i * 16 + lq * 4 + r;
          int col = wc * 64 + j * 16 + lr;
          int byte = row * 256 + (((col >> 3) ^ (row & 7)) << 4) + ((col & 7) << 1);
          tb[byte >> 1] = __builtin_bit_cast(unsigned short, (bf16_t)(acc[i][j][r] + bv[i][r]));
        }
    __builtin_amdgcn_s_barrier();
#pragma unroll
    for (int u = 0; u < 8; ++u) {
      int flat = tid + u * 256;
      int row = flat >> 4, c = flat & 15;
      u32x4 v = *(const u32x4*)(lds + row * 256 + ((c ^ (row & 7)) << 4));
      int m = m0 + row;  // h*64+dv
      int hh = m >> 6, dv = m & 63;
      int n = n0 + c * 8, b = n >> 10, s = n & 1023;
      *(u32x4*)(vt + ((size_t)((b * NH + hh) * 64 + dv)) * S_ + s) = v;
    }
  }
}

// ---------------------------------------------------------------------------
// Flash attention. 512 blocks x 512 threads (8 waves x 16 q-rows).
// bid = qt*64 + (b*8+head): all 8 q-tiles of a (b,head) share an XCD.
// K/V LDS-staged (swizzled), triple-buffered, counted vmcnt; swapped QK^T;
// softmax exp2-domain with defer-rescale (THR=11 in log2 units); per-lane
// partial l; P redistributed via permlane32/16_swap; setprio around MFMA.
// ---------------------------------------------------------------------------
__global__ __launch_bounds__(512) void attn_kernel(
    const bf16_t* __restrict__ qk, const bf16_t* __restrict__ vt,
    bf16_t* __restrict__ ao) {
  __shared__ char lds[49152];
  int bid = blockIdx.x;
  int qt = bid >> 6, g = bid & 63;
  int b = g >> 3, head = g & 7;
  int tid = threadIdx.x, wave = tid >> 6, lane = tid & 63;
  int lr = lane & 15, lq = lane >> 4;
  int qb = qt * 128 + wave * 16;
  const bf16_t* qkb = qk + (size_t)b * S_ * C2_ + head * 128;
  const bf16_t* vtb = vt + (size_t)((b * NH + head) * 64) * S_;

  bf16x8 qf[2];
#pragma unroll
  for (int kk = 0; kk < 2; ++kk)
    qf[kk] = *(const bf16x8*)(qkb + (size_t)(qb + lr) * C2_ + kk * 32 + lq * 8);

  f32x4 oacc[4] = {};
  float m_run = -1e30f, l_run = 0.f;

  char* sb0 = lds;
  char* sb1 = lds + 16384;
  char* sb2 = lds + 32768;

#define STAGE_KV(kt, buf)                                                    \
  do {                                                                       \
    stage_swz512(qkb + (size_t)((kt) * 64) * C2_ + 64, C2_, (buf), tid);     \
    stage_swz512(vtb + (kt) * 64, S_, (buf) + 8192, tid);                    \
  } while (0)

  STAGE_KV(0, sb0);
#pragma unroll 1
  for (int kt = 0; kt < 16; ++kt) {
    if (kt < 15) {
      STAGE_KV(kt + 1, sb1);
      asm volatile("s_waitcnt vmcnt(2)" ::: "memory");
    } else {
      asm volatile("s_waitcnt vmcnt(0)" ::: "memory");
    }
    __builtin_amdgcn_s_barrier();

    // S^T = K Q^T  (Q pre-scaled by 0.125*log2e)
    f32x4 sacc[4] = {};
    __builtin_amdgcn_s_setprio(1);
#pragma unroll
    for (int kk = 0; kk < 2; ++kk) {
      int co = ((kk * 4 + lq) ^ (lr & 7)) << 4;
#pragma unroll
      for (int mf = 0; mf < 4; ++mf) {
        bf16x8 kf = *(const bf16x8*)(sb0 + (mf * 16 + lr) * 128 + co);
        sacc[mf] = __builtin_amdgcn_mfma_f32_16x16x32_bf16(kf, qf[kk], sacc[mf], 0, 0, 0);
      }
    }
    __builtin_amdgcn_s_setprio(0);

    // online softmax; lane owns q-col lr, 16 local t-values
    float mx = -1e30f;
#pragma unroll
    for (int mf = 0; mf < 4; ++mf)
#pragma unroll
      for (int r = 0; r < 4; ++r) mx = fmaxf(mx, sacc[mf][r]);
    mx = fmaxf(mx, __shfl_xor(mx, 16));
    mx = fmaxf(mx, __shfl_xor(mx, 32));
    if (__any(mx - m_run > 11.f)) {       // defer-rescale (T13)
      float mn = fmaxf(m_run, mx);
      float alpha = __builtin_amdgcn_exp2f(m_run - mn);
      m_run = mn;
      l_run *= alpha;
#pragma unroll
      for (int df = 0; df < 4; ++df)
#pragma unroll
        for (int r = 0; r < 4; ++r) oacc[df][r] *= alpha;
    }
    float p[4][4];
    float rs = 0.f;
#pragma unroll
    for (int mf = 0; mf < 4; ++mf)
#pragma unroll
      for (int r = 0; r < 4; ++r) {
        float v = __builtin_amdgcn_exp2f(sacc[mf][r] - m_run);
        p[mf][r] = v; rs += v;
      }
    l_run += rs;                           // per-lane partial; reduced at end
    unsigned pk[4][2];
#pragma unroll
    for (int mf = 0; mf < 4; ++mf)
#pragma unroll
      for (int j = 0; j < 2; ++j)
        pk[mf][j] = pack2(p[mf][2 * j], p[mf][2 * j + 1]);

    // O^T += V^T P^T ; P B-frags via permlane32+permlane16 swaps
#pragma unroll
    for (int kk = 0; kk < 2; ++kk) {
      int co = ((kk * 4 + lq) ^ (lr & 7)) << 4;
      bf16x8 vf[4];
#pragma unroll
      for (int df = 0; df < 4; ++df)
        vf[df] = *(const bf16x8*)(sb0 + 8192 + (df * 16 + lr) * 128 + co);
      unsigned w0 = pk[2 * kk + 0][0], w2 = pk[2 * kk + 1][0];
      unsigned w1 = pk[2 * kk + 0][1], w3 = pk[2 * kk + 1][1];
      asm("v_permlane32_swap_b32 %0, %1" : "+v"(w0), "+v"(w2));
      asm("v_permlane16_swap_b32 %0, %1" : "+v"(w0), "+v"(w2));
      asm("v_permlane32_swap_b32 %0, %1" : "+v"(w1), "+v"(w3));
      asm("v_permlane16_swap_b32 %0, %1" : "+v"(w1), "+v"(w3));
      u32x4 bw; bw[0] = w0; bw[1] = w1; bw[2] = w2; bw[3] = w3;
      bf16x8 pb = __builtin_bit_cast(bf16x8, bw);
      __builtin_amdgcn_s_setprio(1);
#pragma unroll
      for (int df = 0; df < 4; ++df)
        oacc[df] = __builtin_amdgcn_mfma_f32_16x16x32_bf16(vf[df], pb, oacc[df], 0, 0, 0);
      __builtin_amdgcn_s_setprio(0);
    }
    char* tp = sb0; sb0 = sb1; sb1 = sb2; sb2 = tp;
  }

  // epilogue: reduce per-lane l partials, then write O^T
  float lt = l_run;
  lt += __shfl_xor(lt, 16);
  lt += __shfl_xor(lt, 32);
  float inv = 1.f / lt;
  bf16_t* aop = ao + ((size_t)b * S_ + qb + lr) * C_ + head * 64;
#pragma unroll
  for (int df = 0; df < 4; ++df)
#pragma unroll
    for (int rp = 0; rp < 4; rp += 2) {
      unsigned u = pack2(oacc[df][rp] * inv, oacc[df][rp + 1] * inv);
      *(unsigned*)(aop + df * 16 + lq * 4 + rp) = u;
    }
#undef STAGE_KV
}

// ---------------------------------------------------------------------------
// Out projection + bias + residual: out[b][d][s] = x + b_out[d] + ao @ W_out
// 512 blocks, 64m x 128n tiles; bid = n*128 + m so same-ao-panel blocks
// share an XCD.
// ---------------------------------------------------------------------------
__global__ __launch_bounds__(256) void gemm_out_kernel(
    const bf16_t* __restrict__ A, const bf16_t* __restrict__ Bw,
    const float* __restrict__ bias, const float* __restrict__ xres,
    float* __restrict__ out) {
  __shared__ char lds[49152];
  int tid = threadIdx.x;
  int bid = blockIdx.x;
  int m0 = (bid & 127) * 64, n0 = (bid >> 7) * 128;
  f32x4 acc[2][4] = {};
  gemm_loop<2, 4>(A + (size_t)m0 * C_, C_, Bw + (size_t)n0 * C_, C_, lds, tid, acc);
  int wave = tid >> 6, lane = tid & 63;
  int wr = wave >> 1, wc = wave & 1, lr = lane & 15, lq = lane >> 4;
#pragma unroll
  for (int i = 0; i < 2; ++i) {
#pragma unroll
    for (int j = 0; j < 4; ++j) {
      int d = n0 + wc * 64 + j * 16 + lr;
      int m = m0 + wr * 32 + i * 16 + lq * 4;
      int b = m >> 10, s = m & 1023;
      size_t o = ((size_t)b * C_ + d) * S_ + s;
      f32x4 res = *(const f32x4*)(xres + o);
      f32x4 val;
      float bd = bias[d];
#pragma unroll
      for (int r = 0; r < 4; ++r) val[r] = res[r] + bd + acc[i][j][r];
      *(f32x4*)(out + o) = val;
    }
  }
}

// ---------------------------------------------------------------------------
extern "C" void kernel_launch(void* const* d_in, const int* in_sizes, int n_in,
                              void* d_out, int out_size, void* d_ws, size_t ws_size,
                              hipStream_t stream) {
  const float* x        = (const float*)d_in[0];
  const float* gn_scale = (const float*)d_in[1];
  const float* gn_bias  = (const float*)d_in[2];
  const float* W_qkv    = (const float*)d_in[3];
  const float* b_qkv    = (const float*)d_in[4];
  const float* W_out    = (const float*)d_in[5];
  const float* b_out    = (const float*)d_in[6];
  float* out = (float*)d_out;

  char* ws = (char*)d_ws;
  bf16_t* h_t   = (bf16_t*)(ws);               // 8 MiB  [b][s][c]
  bf16_t* qk_t  = (bf16_t*)(ws + 8388608);     // 16 MiB [b][s][h*128+det]
  bf16_t* vt    = (bf16_t*)(ws + 25165824);    // 8 MiB  [b][h][dv][s]
  bf16_t* ao_t  = (bf16_t*)(ws + 33554432);    // 8 MiB  [b][s][c]
  bf16_t* wqkvp = (bf16_t*)(ws + 41943040);    // 1.5 MiB [d'][c] permuted
  bf16_t* woutt = (bf16_t*)(ws + 43515904);    // 0.5 MiB [d][c]
  float* bqp = (float*)d_out;  // 1536 f32 bias, overwritten later by gemm_out

  prep_wqkv_kernel<<<dim3(48, 16), 256, 0, stream>>>(W_qkv, b_qkv, wqkvp, bqp);
  transpose_w_kernel<<<dim3(16, 16), 256, 0, stream>>>(W_out, woutt, C_, C_);
  gn_kernel<<<256, 256, 0, stream>>>(x, gn_scale, gn_bias, h_t);
  gemm_qkv_kernel<<<768, 256, 0, stream>>>(h_t, wqkvp, bqp, qk_t, vt);
  attn_kernel<<<512, 512, 0, stream>>>(qk_t, vt, ao_t);
  gemm_out_kernel<<<512, 256, 0, stream>>>(ao_t, woutt, b_out, x, out);
}

// Round 6
// 75.370 us; speedup vs baseline: 3.9400x; 1.0908x over previous
//
#include <hip/hip_runtime.h>
#include <hip/hip_bf16.h>

typedef __bf16 bf16_t;
typedef __attribute__((ext_vector_type(8))) __bf16 bf16x8;
typedef __attribute__((ext_vector_type(4))) float f32x4;
typedef __attribute__((ext_vector_type(4))) unsigned int u32x4;

#define B_   8
#define C_   512
#define S_   1024
#define NH   8
#define C2_  1024
#define C3_  1536
#define QSCALE 0.1803368801111204f  // 0.125 * log2(e): softmax in exp2 domain

static __device__ __forceinline__ unsigned pack2(float a, float b) {
  unsigned short lo = __builtin_bit_cast(unsigned short, (bf16_t)a);
  unsigned short hi = __builtin_bit_cast(unsigned short, (bf16_t)b);
  return (unsigned)lo | ((unsigned)hi << 16);
}

static __device__ __forceinline__ void load_lds16(const void* g, void* l) {
  __builtin_amdgcn_global_load_lds(
      (const __attribute__((address_space(1))) unsigned*)g,
      (__attribute__((address_space(3))) unsigned*)l, 16, 0, 0);
}

// Stage ROUNDS*256 16B chunks into LDS (256-thread blocks). Rows are 128B
// (8 chunks); source chunk XOR-swizzled (c ^ row&7) so ds_read_b128 frags
// are conflict-free while the LDS dest stays linear (m173 pattern).
template<int ROUNDS>
static __device__ __forceinline__ void stage_swz(const bf16_t* g, int rstride,
                                                 char* lbuf, int tid) {
#pragma unroll
  for (int r = 0; r < ROUNDS; ++r) {
    int i = r * 256 + tid;
    int row = i >> 3;
    int cg = (i & 7) ^ (row & 7);
    load_lds16(g + (size_t)row * rstride + cg * 8,
               lbuf + r * 4096 + (tid & 192) * 16);  // wave-uniform base
  }
}

// 512-thread variant: one round covers 512 chunks = 64 rows = 8 KB.
static __device__ __forceinline__ void stage_swz512(const bf16_t* g, int rstride,
                                                    char* lbuf, int tid) {
  int row = tid >> 3;
  int cg = (tid & 7) ^ (row & 7);
  load_lds16(g + (size_t)row * rstride + cg * 8,
             lbuf + (tid & 448) * 16);  // wave-uniform base
}

// ---------------------------------------------------------------------------
// Merged prep: [0,256) GroupNorm+transpose, [256,1024) W_qkv prep,
// [1024,1280) W_out transpose. All independent; one launch kills two
// serialization gaps.
// ---------------------------------------------------------------------------
__global__ __launch_bounds__(256) void prep_kernel(
    const float* __restrict__ x, const float* __restrict__ gsc,
    const float* __restrict__ gbi, const float* __restrict__ Wq,
    const float* __restrict__ bq, const float* __restrict__ Wo,
    bf16_t* __restrict__ h_t, bf16_t* __restrict__ wqkvp,
    bf16_t* __restrict__ woutt, float* __restrict__ bqp) {
  __shared__ __align__(16) char smem[65568];
  int bid = blockIdx.x;
  int tid = threadIdx.x;
  if (bid < 256) {
    // ---- GroupNorm + bf16 + transpose: x[b][c][s] -> h_t[b][s][c]
    float* xs = (float*)smem;
    float* red = (float*)(smem + 65536);
    int b = bid >> 5, g = bid & 31;
    const f32x4* xb4 = (const f32x4*)(x + ((size_t)b * C_ + g * 16) * S_);
    float s = 0.f, s2 = 0.f;
#pragma unroll
    for (int k = 0; k < 16; ++k) {
      int vf = k * 256 + tid;
      f32x4 v = xb4[vf];
      ((f32x4*)xs)[vf] = v;
#pragma unroll
      for (int e = 0; e < 4; ++e) { s += v[e]; s2 += v[e] * v[e]; }
    }
    for (int off = 32; off > 0; off >>= 1) {
      s  += __shfl_down(s, off);
      s2 += __shfl_down(s2, off);
    }
    int wave = tid >> 6, lane = tid & 63;
    if (lane == 0) { red[wave] = s; red[4 + wave] = s2; }
    __syncthreads();
    float ts = red[0] + red[1] + red[2] + red[3];
    float t2 = red[4] + red[5] + red[6] + red[7];
    const float inv_n = 1.f / (16.f * S_);
    float mean = ts * inv_n;
    float var  = t2 * inv_n - mean * mean;
    float rstd = rsqrtf(var + 1e-6f);
    float ac[16], bc[16];
#pragma unroll
    for (int cl = 0; cl < 16; ++cl) {
      float sc = gsc[g * 16 + cl] * rstd;
      ac[cl] = sc;
      bc[cl] = gbi[g * 16 + cl] - mean * sc;
    }
#pragma unroll
    for (int k = 0; k < 4; ++k) {
      int srow = tid + k * 256;
      unsigned ow[8];
#pragma unroll
      for (int p = 0; p < 8; ++p) {
        float y0 = xs[(2 * p    ) * 1024 + srow] * ac[2 * p    ] + bc[2 * p    ];
        float y1 = xs[(2 * p + 1) * 1024 + srow] * ac[2 * p + 1] + bc[2 * p + 1];
        ow[p] = pack2(y0, y1);
      }
      bf16_t* dst = h_t + ((size_t)b * S_ + srow) * C_ + g * 16;
      u32x4 v0, v1;
#pragma unroll
      for (int e = 0; e < 4; ++e) { v0[e] = ow[e]; v1[e] = ow[4 + e]; }
      *(u32x4*)dst = v0;
      *(u32x4*)(dst + 8) = v1;
    }
  } else if (bid < 1024) {
    // ---- W_qkv: transpose + permute d->d'=part*512+h*64+dq, fold QSCALE
    float* T = (float*)smem;
    int id = bid - 256;
    int d0 = (id % 48) * 32, c0 = (id / 48) * 32;
    int ld = tid & 31, lc = tid >> 5;
#pragma unroll
    for (int i = 0; i < 4; ++i) {
      int c = lc + i * 8;
      T[c * 33 + ld] = Wq[(size_t)(c0 + c) * C3_ + d0 + ld];
    }
    __syncthreads();
#pragma unroll
    for (int i = 0; i < 4; ++i) {
      int dd = lc + i * 8;
      int d = d0 + dd;
      int h = d / 192, rr = d - h * 192, part = rr >> 6, dq = rr & 63;
      float scl = (part == 0) ? QSCALE : 1.f;
      wqkvp[(size_t)(part * 512 + h * 64 + dq) * C_ + c0 + ld] =
          (bf16_t)(T[ld * 33 + dd] * scl);
    }
    if (id < 48 && tid < 32) {
      int d = d0 + tid;
      int h = d / 192, rr = d - h * 192, part = rr >> 6, dq = rr & 63;
      bqp[part * 512 + h * 64 + dq] = bq[d] * ((part == 0) ? QSCALE : 1.f);
    }
  } else {
    // ---- W_out transpose: Wo[512 c][512 d] f32 -> woutt[d][c] bf16
    float* T = (float*)smem;
    int id = bid - 1024;
    int c0 = (id & 15) * 32, r0 = (id >> 4) * 32;
    int lc = tid & 31, lr = tid >> 5;
#pragma unroll
    for (int i = 0; i < 4; ++i) {
      int r = lr + i * 8;
      T[r * 33 + lc] = Wo[(size_t)(r0 + r) * C_ + c0 + lc];
    }
    __syncthreads();
#pragma unroll
    for (int i = 0; i < 4; ++i) {
      int cc = lr + i * 8;
      woutt[(size_t)(c0 + cc) * C_ + r0 + lc] = (bf16_t)T[lc * 33 + cc];
    }
  }
}

// ---------------------------------------------------------------------------
// Templated staged-GEMM mainloop: C[MF*32 m][NF*32 n] = A[m][k]*B[n][k], K=512.
// BK=64, double-buffered global_load_lds staging, counted vmcnt, raw barriers.
// 256 threads as 2x2 waves; per wave MF x NF 16x16 frags.
// ---------------------------------------------------------------------------
template<int MF, int NF>
static __device__ __forceinline__ void gemm_loop(
    const bf16_t* Asrc, int Astride, const bf16_t* Bsrc, int Bstride,
    char* lds, int tid, f32x4 (&acc)[MF][NF]) {
  int wave = tid >> 6, lane = tid & 63;
  int wr = wave >> 1, wc = wave & 1;
  int lr = lane & 15, lq = lane >> 4;
  char* A0 = lds;
  char* B0 = lds + MF * 4096;
  char* A1 = lds + (MF + NF) * 4096;
  char* B1 = lds + (2 * MF + NF) * 4096;
  stage_swz<MF>(Asrc, Astride, A0, tid);
  stage_swz<NF>(Bsrc, Bstride, B0, tid);
#pragma unroll 1
  for (int ks = 0; ks < 8; ++ks) {
    if (ks < 7) {
      stage_swz<MF>(Asrc + (ks + 1) * 64, Astride, (ks & 1) ? A0 : A1, tid);
      stage_swz<NF>(Bsrc + (ks + 1) * 64, Bstride, (ks & 1) ? B0 : B1, tid);
      asm volatile("s_waitcnt vmcnt(%0)" :: "i"(MF + NF) : "memory");
    } else {
      asm volatile("s_waitcnt vmcnt(0)" ::: "memory");
    }
    __builtin_amdgcn_s_barrier();
    const char* Ab = (ks & 1) ? A1 : A0;
    const char* Bb = (ks & 1) ? B1 : B0;
#pragma unroll
    for (int kk = 0; kk < 2; ++kk) {
      int co = ((kk * 4 + lq) ^ (lr & 7)) << 4;
      bf16x8 a[MF], b[NF];
#pragma unroll
      for (int i = 0; i < MF; ++i)
        a[i] = *(const bf16x8*)(Ab + (wr * MF * 16 + i * 16 + lr) * 128 + co);
#pragma unroll
      for (int j = 0; j < NF; ++j)
        b[j] = *(const bf16x8*)(Bb + (wc * NF * 16 + j * 16 + lr) * 128 + co);
#pragma unroll
      for (int i = 0; i < MF; ++i)
#pragma unroll
        for (int j = 0; j < NF; ++j)
          acc[i][j] = __builtin_amdgcn_mfma_f32_16x16x32_bf16(a[i], b[j], acc[i][j], 0, 0, 0);
    }
    __builtin_amdgcn_s_barrier();
  }
}

// ---------------------------------------------------------------------------
// Merged QKV projection. 1-D grid, 768 blocks, XCD-grouped (same h_t panel
// -> same XCD). bid<512: QK role -> qk[b][s][h*128+det]; else V role
// (swapped operands) -> vt[b][h][dv][s].
// ---------------------------------------------------------------------------
__global__ __launch_bounds__(256) void gemm_qkv_kernel(
    const bf16_t* __restrict__ h, const bf16_t* __restrict__ wq,
    const float* __restrict__ bias, bf16_t* __restrict__ qk,
    bf16_t* __restrict__ vt) {
  __shared__ char lds[65536];
  int tid = threadIdx.x;
  int bid = blockIdx.x;
  int wave = tid >> 6, lane = tid & 63;
  int wr = wave >> 1, wc = wave & 1, lr = lane & 15, lq = lane >> 4;
  unsigned short* tb = (unsigned short*)lds;
  if (bid < 512) {
    int m0 = (bid & 63) * 128, n0 = (bid >> 6) * 128;
    f32x4 acc[4][4] = {};
    gemm_loop<4, 4>(h + (size_t)m0 * C_, C_, wq + (size_t)n0 * C_, C_, lds, tid, acc);
    float bv[4];
#pragma unroll
    for (int j = 0; j < 4; ++j) bv[j] = bias[n0 + wc * 64 + j * 16 + lr];
#pragma unroll
    for (int i = 0; i < 4; ++i)
#pragma unroll
      for (int j = 0; j < 4; ++j)
#pragma unroll
        for (int r = 0; r < 4; ++r) {
          int row = wr * 64 + i * 16 + lq * 4 + r;
          int col = wc * 64 + j * 16 + lr;
          int byte = row * 256 + (((col >> 3) ^ (row & 7)) << 4) + ((col & 7) << 1);
          tb[byte >> 1] = __builtin_bit_cast(unsigned short, (bf16_t)(acc[i][j][r] + bv[j]));
        }
    __builtin_amdgcn_s_barrier();
#pragma unroll
    for (int u = 0; u < 8; ++u) {
      int flat = tid + u * 256;
      int row = flat >> 4, c = flat & 15;
      u32x4 v = *(const u32x4*)(lds + row * 256 + ((c ^ (row & 7)) << 4));
      int m = m0 + row, b = m >> 10, s = m & 1023;
      int d = n0 + c * 8;
      int hh = (d >> 6) & 7, det = ((d >> 9) << 6) + (d & 63);
      *(u32x4*)(qk + ((size_t)(b * S_ + s)) * C2_ + hh * 128 + det) = v;
    }
  } else {
    int j2 = bid - 512;
    int n0 = (j2 & 63) * 128, m0 = (j2 >> 6) * 128;
    f32x4 acc[4][4] = {};
    gemm_loop<4, 4>(wq + (size_t)(1024 + m0) * C_, C_, h + (size_t)n0 * C_, C_, lds, tid, acc);
    float bv[4][4];
#pragma unroll
    for (int i = 0; i < 4; ++i) {
      f32x4 t = *(const f32x4*)(bias + 1024 + m0 + wr * 64 + i * 16 + lq * 4);
#pragma unroll
      for (int r = 0; r < 4; ++r) bv[i][r] = t[r];
    }
#pragma unroll
    for (int i = 0; i < 4; ++i)
#pragma unroll
      for (int j = 0; j < 4; ++j)
#pragma unroll
        for (int r = 0; r < 4; ++r) {
          int row = wr * 64 + i * 16 + lq * 4 + r;
          int col = wc * 64 + j * 16 + lr;
          int byte = row * 256 + (((col >> 3) ^ (row & 7)) << 4) + ((col & 7) << 1);
          tb[byte >> 1] = __builtin_bit_cast(unsigned short, (bf16_t)(acc[i][j][r] + bv[i][r]));
        }
    __builtin_amdgcn_s_barrier();
#pragma unroll
    for (int u = 0; u < 8; ++u) {
      int flat = tid + u * 256;
      int row = flat >> 4, c = flat & 15;
      u32x4 v = *(const u32x4*)(lds + row * 256 + ((c ^ (row & 7)) << 4));
      int m = m0 + row;  // h*64+dv
      int hh = m >> 6, dv = m & 63;
      int n = n0 + c * 8, b = n >> 10, s = n & 1023;
      *(u32x4*)(vt + ((size_t)((b * NH + hh) * 64 + dv)) * S_ + s) = v;
    }
  }
}

// ---------------------------------------------------------------------------
// Flash attention. 256 blocks x 512 threads (8 waves x 32 q-rows).
// bid = qt*64 + (b*8+head): the 4 q-tiles of a (b,head) share an XCD.
// K/V LDS-staged (swizzled), 4 buffers, 2-deep prefetch (vmcnt(4));
// swapped QK^T; exp2-domain softmax with defer-rescale; per-lane partial l;
// P redistributed via permlane32/16_swap; setprio around MFMA clusters.
// Each wave reads K/V frags once and feeds TWO q-frags -> half the
// LDS-read traffic per unit work vs 16 q/wave.
// ---------------------------------------------------------------------------
__global__ __launch_bounds__(512) void attn_kernel(
    const bf16_t* __restrict__ qk, const bf16_t* __restrict__ vt,
    bf16_t* __restrict__ ao) {
  __shared__ char lds[65536];
  int bid = blockIdx.x;
  int qt = bid >> 6, g = bid & 63;
  int b = g >> 3, head = g & 7;
  int tid = threadIdx.x, wave = tid >> 6, lane = tid & 63;
  int lr = lane & 15, lq = lane >> 4;
  int qb = qt * 256 + wave * 32;
  const bf16_t* qkb = qk + (size_t)b * S_ * C2_ + head * 128;
  const bf16_t* vtb = vt + (size_t)((b * NH + head) * 64) * S_;

  bf16x8 qf[2][2];
#pragma unroll
  for (int q2 = 0; q2 < 2; ++q2)
#pragma unroll
    for (int kk = 0; kk < 2; ++kk)
      qf[q2][kk] = *(const bf16x8*)(qkb + (size_t)(qb + q2 * 16 + lr) * C2_ + kk * 32 + lq * 8);

  f32x4 oacc[2][4] = {};
  float m_run[2] = {-1e30f, -1e30f}, l_run[2] = {0.f, 0.f};

  char* s0 = lds;
  char* s1 = lds + 16384;
  char* s2 = lds + 32768;
  char* s3 = lds + 49152;

#define STAGE_KV(kt, buf)                                                    \
  do {                                                                       \
    stage_swz512(qkb + (size_t)((kt) * 64) * C2_ + 64, C2_, (buf), tid);     \
    stage_swz512(vtb + (kt) * 64, S_, (buf) + 8192, tid);                    \
  } while (0)

  STAGE_KV(0, s0);
  STAGE_KV(1, s1);
#pragma unroll 1
  for (int kt = 0; kt < 16; ++kt) {
    if (kt < 14) {
      STAGE_KV(kt + 2, s2);
      asm volatile("s_waitcnt vmcnt(4)" ::: "memory");
    } else if (kt == 14) {
      asm volatile("s_waitcnt vmcnt(2)" ::: "memory");
    } else {
      asm volatile("s_waitcnt vmcnt(0)" ::: "memory");
    }
    __builtin_amdgcn_s_barrier();

    // S^T = K Q^T  (Q pre-scaled by 0.125*log2e)
    f32x4 sacc[2][4] = {};
    __builtin_amdgcn_s_setprio(1);
#pragma unroll
    for (int kk = 0; kk < 2; ++kk) {
      int co = ((kk * 4 + lq) ^ (lr & 7)) << 4;
      bf16x8 kf[4];
#pragma unroll
      for (int mf = 0; mf < 4; ++mf)
        kf[mf] = *(const bf16x8*)(s0 + (mf * 16 + lr) * 128 + co);
#pragma unroll
      for (int q2 = 0; q2 < 2; ++q2)
#pragma unroll
        for (int mf = 0; mf < 4; ++mf)
          sacc[q2][mf] = __builtin_amdgcn_mfma_f32_16x16x32_bf16(kf[mf], qf[q2][kk], sacc[q2][mf], 0, 0, 0);
    }
    __builtin_amdgcn_s_setprio(0);

    // online softmax; lane owns q-col (q2,lr), 16 local t-values each
    float mx[2];
#pragma unroll
    for (int q2 = 0; q2 < 2; ++q2) {
      float m = -1e30f;
#pragma unroll
      for (int mf = 0; mf < 4; ++mf)
#pragma unroll
        for (int r = 0; r < 4; ++r) m = fmaxf(m, sacc[q2][mf][r]);
      m = fmaxf(m, __shfl_xor(m, 16));
      m = fmaxf(m, __shfl_xor(m, 32));
      mx[q2] = m;
    }
    if (__any(fmaxf(mx[0] - m_run[0], mx[1] - m_run[1]) > 11.f)) {  // T13
#pragma unroll
      for (int q2 = 0; q2 < 2; ++q2) {
        float mn = fmaxf(m_run[q2], mx[q2]);
        float alpha = __builtin_amdgcn_exp2f(m_run[q2] - mn);
        m_run[q2] = mn;
        l_run[q2] *= alpha;
#pragma unroll
        for (int df = 0; df < 4; ++df)
#pragma unroll
          for (int r = 0; r < 4; ++r) oacc[q2][df][r] *= alpha;
      }
    }
    unsigned pk[2][4][2];
#pragma unroll
    for (int q2 = 0; q2 < 2; ++q2) {
      float p[4][4];
      float rs = 0.f;
#pragma unroll
      for (int mf = 0; mf < 4; ++mf)
#pragma unroll
        for (int r = 0; r < 4; ++r) {
          float v = __builtin_amdgcn_exp2f(sacc[q2][mf][r] - m_run[q2]);
          p[mf][r] = v; rs += v;
        }
      l_run[q2] += rs;                     // per-lane partial; reduced at end
#pragma unroll
      for (int mf = 0; mf < 4; ++mf)
#pragma unroll
        for (int j = 0; j < 2; ++j)
          pk[q2][mf][j] = pack2(p[mf][2 * j], p[mf][2 * j + 1]);
    }

    // O^T += V^T P^T ; P B-frags via permlane32+permlane16 swaps
#pragma unroll
    for (int kk = 0; kk < 2; ++kk) {
      int co = ((kk * 4 + lq) ^ (lr & 7)) << 4;
      bf16x8 vf[4];
#pragma unroll
      for (int df = 0; df < 4; ++df)
        vf[df] = *(const bf16x8*)(s0 + 8192 + (df * 16 + lr) * 128 + co);
#pragma unroll
      for (int q2 = 0; q2 < 2; ++q2) {
        unsigned w0 = pk[q2][2 * kk + 0][0], w2 = pk[q2][2 * kk + 1][0];
        unsigned w1 = pk[q2][2 * kk + 0][1], w3 = pk[q2][2 * kk + 1][1];
        asm("v_permlane32_swap_b32 %0, %1" : "+v"(w0), "+v"(w2));
        asm("v_permlane16_swap_b32 %0, %1" : "+v"(w0), "+v"(w2));
        asm("v_permlane32_swap_b32 %0, %1" : "+v"(w1), "+v"(w3));
        asm("v_permlane16_swap_b32 %0, %1" : "+v"(w1), "+v"(w3));
        u32x4 bw; bw[0] = w0; bw[1] = w1; bw[2] = w2; bw[3] = w3;
        bf16x8 pb = __builtin_bit_cast(bf16x8, bw);
        __builtin_amdgcn_s_setprio(1);
#pragma unroll
        for (int df = 0; df < 4; ++df)
          oacc[q2][df] = __builtin_amdgcn_mfma_f32_16x16x32_bf16(vf[df], pb, oacc[q2][df], 0, 0, 0);
        __builtin_amdgcn_s_setprio(0);
      }
    }
    char* tp = s0; s0 = s1; s1 = s2; s2 = s3; s3 = tp;
  }

  // epilogue: reduce per-lane l partials, write O^T
#pragma unroll
  for (int q2 = 0; q2 < 2; ++q2) {
    float lt = l_run[q2];
    lt += __shfl_xor(lt, 16);
    lt += __shfl_xor(lt, 32);
    float inv = 1.f / lt;
    bf16_t* aop = ao + ((size_t)b * S_ + qb + q2 * 16 + lr) * C_ + head * 64;
#pragma unroll
    for (int df = 0; df < 4; ++df)
#pragma unroll
      for (int rp = 0; rp < 4; rp += 2) {
        unsigned u = pack2(oacc[q2][df][rp] * inv, oacc[q2][df][rp + 1] * inv);
        *(unsigned*)(aop + df * 16 + lq * 4 + rp) = u;
      }
  }
#undef STAGE_KV
}

// ---------------------------------------------------------------------------
// Out projection + bias + residual: out[b][d][s] = x + b_out[d] + ao @ W_out
// 512 blocks, 64m x 128n tiles; bid = n*128 + m so same-ao-panel blocks
// share an XCD.
// ---------------------------------------------------------------------------
__global__ __launch_bounds__(256) void gemm_out_kernel(
    const bf16_t* __restrict__ A, const bf16_t* __restrict__ Bw,
    const float* __restrict__ bias, const float* __restrict__ xres,
    float* __restrict__ out) {
  __shared__ char lds[49152];
  int tid = threadIdx.x;
  int bid = blockIdx.x;
  int m0 = (bid & 127) * 64, n0 = (bid >> 7) * 128;
  f32x4 acc[2][4] = {};
  gemm_loop<2, 4>(A + (size_t)m0 * C_, C_, Bw + (size_t)n0 * C_, C_, lds, tid, acc);
  int wave = tid >> 6, lane = tid & 63;
  int wr = wave >> 1, wc = wave & 1, lr = lane & 15, lq = lane >> 4;
#pragma unroll
  for (int i = 0; i < 2; ++i) {
#pragma unroll
    for (int j = 0; j < 4; ++j) {
      int d = n0 + wc * 64 + j * 16 + lr;
      int m = m0 + wr * 32 + i * 16 + lq * 4;
      int b = m >> 10, s = m & 1023;
      size_t o = ((size_t)b * C_ + d) * S_ + s;
      f32x4 res = *(const f32x4*)(xres + o);
      f32x4 val;
      float bd = bias[d];
#pragma unroll
      for (int r = 0; r < 4; ++r) val[r] = res[r] + bd + acc[i][j][r];
      *(f32x4*)(out + o) = val;
    }
  }
}

// ---------------------------------------------------------------------------
extern "C" void kernel_launch(void* const* d_in, const int* in_sizes, int n_in,
                              void* d_out, int out_size, void* d_ws, size_t ws_size,
                              hipStream_t stream) {
  const float* x        = (const float*)d_in[0];
  const float* gn_scale = (const float*)d_in[1];
  const float* gn_bias  = (const float*)d_in[2];
  const float* W_qkv    = (const float*)d_in[3];
  const float* b_qkv    = (const float*)d_in[4];
  const float* W_out    = (const float*)d_in[5];
  const float* b_out    = (const float*)d_in[6];
  float* out = (float*)d_out;

  char* ws = (char*)d_ws;
  bf16_t* h_t   = (bf16_t*)(ws);               // 8 MiB  [b][s][c]
  bf16_t* qk_t  = (bf16_t*)(ws + 8388608);     // 16 MiB [b][s][h*128+det]
  bf16_t* vt    = (bf16_t*)(ws + 25165824);    // 8 MiB  [b][h][dv][s]
  bf16_t* ao_t  = (bf16_t*)(ws + 33554432);    // 8 MiB  [b][s][c]
  bf16_t* wqkvp = (bf16_t*)(ws + 41943040);    // 1.5 MiB [d'][c] permuted
  bf16_t* woutt = (bf16_t*)(ws + 43515904);    // 0.5 MiB [d][c]
  float* bqp = (float*)d_out;  // 1536 f32 bias, overwritten later by gemm_out

  prep_kernel<<<1280, 256, 0, stream>>>(x, gn_scale, gn_bias, W_qkv, b_qkv,
                                        W_out, h_t, wqkvp, woutt, bqp);
  gemm_qkv_kernel<<<768, 256, 0, stream>>>(h_t, wqkvp, bqp, qk_t, vt);
  attn_kernel<<<256, 512, 0, stream>>>(qk_t, vt, ao_t);
  gemm_out_kernel<<<512, 256, 0, stream>>>(ao_t, woutt, b_out, x, out);
}